// Round 2
// baseline (1279.650 us; speedup 1.0000x reference)
//
#include <hip/hip_runtime.h>
#include <cstdint>
#include <cstddef>

#define DIN 128   // feature width of all layer inputs (and Q/K/V width = H*DH)
#define QKVS_STRIDE 512

// ---------------- CSR build ----------------
__global__ void k_zero(int* __restrict__ a, int n){
  int i = blockIdx.x*blockDim.x + threadIdx.x;
  if(i<n) a[i]=0;
}

__global__ void k_count(const int* __restrict__ dst, int* __restrict__ deg, int E){
  int i = blockIdx.x*blockDim.x + threadIdx.x;
  if(i<E) atomicAdd(&deg[dst[i]], 1);
}

__global__ void k_scan1(const int* __restrict__ deg, int* __restrict__ offs,
                        int* __restrict__ part, int n){
  __shared__ int sm[256];
  int t = threadIdx.x; int g = blockIdx.x*256 + t;
  int v = (g<n)? deg[g] : 0;
  sm[t] = v;
  for(int o=1;o<256;o<<=1){
    __syncthreads();
    int x = (t>=o)? sm[t-o] : 0;
    __syncthreads();
    sm[t] += x;
  }
  __syncthreads();
  if(g<n) offs[g+1] = sm[t];
  if(t==255) part[blockIdx.x] = sm[255];
}

__global__ void k_scan2(int* __restrict__ part, int nb){
  __shared__ int sm[256];
  int t=threadIdx.x;
  int v = (t<nb)? part[t] : 0;
  sm[t]=v;
  for(int o=1;o<256;o<<=1){ __syncthreads(); int x=(t>=o)?sm[t-o]:0; __syncthreads(); sm[t]+=x; }
  __syncthreads();
  if(t<nb) part[t] = sm[t]-v;  // exclusive prefix of block totals
}

__global__ void k_scan3(int* __restrict__ offs, const int* __restrict__ part, int n){
  int t=threadIdx.x; int g=blockIdx.x*256+t;
  if(g<n) offs[g+1] += part[blockIdx.x];
  if(g==0) offs[0]=0;
}

__global__ void k_scatter(const int* __restrict__ src, const int* __restrict__ dst,
                          const int* __restrict__ offs, int* __restrict__ cur,
                          int* __restrict__ srcs, int E){
  int i=blockIdx.x*blockDim.x+threadIdx.x;
  if(i<E){
    int d = dst[i];
    int p = atomicAdd(&cur[d],1);
    srcs[offs[d]+p] = src[i];
  }
}

// ---------------- fused QKVS GEMM (fp32) ----------------
// out[N][512]: cols 0..127 = Q, 128..255 = K, 256..383 = V, 384.. = S (ws_cols wide)
// grid: (8, row_tiles): blockIdx.x -> mat = bx>>1 (0..3), col-tile = bx&1
__global__ __launch_bounds__(256,2) void k_gemm(
  const float* __restrict__ X, int nrows,
  const float* __restrict__ Wq, const float* __restrict__ bq,
  const float* __restrict__ Wk, const float* __restrict__ bk,
  const float* __restrict__ Wv, const float* __restrict__ bv,
  const float* __restrict__ Ws, const float* __restrict__ bs,
  int ws_cols, float* __restrict__ out)
{
  __shared__ float Xs[64][128];
  __shared__ float Wsh[128][64];
  int t = threadIdx.x;
  int mat = blockIdx.x >> 1, ct = blockIdx.x & 1;
  int wcols = (mat==3)? ws_cols : 128;
  int col0 = ct*64;
  if(col0 >= wcols) return;
  const float* W; const float* b;
  if(mat==0){W=Wq;b=bq;} else if(mat==1){W=Wk;b=bk;} else if(mat==2){W=Wv;b=bv;} else {W=Ws;b=bs;}
  int row0 = blockIdx.y*64;
  {
    int r = t>>5, c4 = (t&31)<<2;
    #pragma unroll
    for(int j=0;j<8;j++){
      int rr = r + (j<<3); int gr = row0+rr;
      float4 v = make_float4(0.f,0.f,0.f,0.f);
      if(gr < nrows) v = *(const float4*)(X + (size_t)gr*DIN + c4);
      *(float4*)&Xs[rr][c4] = v;
    }
    int k0 = t>>4, cc = (t&15)<<2;
    #pragma unroll
    for(int j=0;j<8;j++){
      int kk = k0 + (j<<4); int gc = col0 + cc;
      float4 v = make_float4(0.f,0.f,0.f,0.f);
      if(gc+3 < wcols) v = *(const float4*)(W + (size_t)kk*wcols + gc);
      *(float4*)&Wsh[kk][cc] = v;
    }
  }
  __syncthreads();
  int tr = t>>4, tc = t&15;
  int r0 = tr<<2, c0 = tc<<2;
  float acc[4][4];
  #pragma unroll
  for(int i=0;i<4;i++){ acc[i][0]=0.f; acc[i][1]=0.f; acc[i][2]=0.f; acc[i][3]=0.f; }
  #pragma unroll 8
  for(int k=0;k<128;k++){
    float4 w4 = *(const float4*)&Wsh[k][c0];
    #pragma unroll
    for(int i=0;i<4;i++){
      float x = Xs[r0+i][k];
      acc[i][0] += x*w4.x; acc[i][1] += x*w4.y; acc[i][2] += x*w4.z; acc[i][3] += x*w4.w;
    }
  }
  int cbase = col0 + c0;
  if(cbase+3 < wcols || wcols==128){
    float4 bb = *(const float4*)(b + cbase);
    #pragma unroll
    for(int i=0;i<4;i++){
      int gr = row0 + r0 + i;
      if(gr < nrows){
        float4 o = make_float4(acc[i][0]+bb.x, acc[i][1]+bb.y, acc[i][2]+bb.z, acc[i][3]+bb.w);
        *(float4*)(out + (size_t)gr*QKVS_STRIDE + mat*128 + cbase) = o;
      }
    }
  }
}

// ---------------- per-node attention (online softmax, CSR) ----------------
// one wave (64 lanes) per dst node; 4 waves / 256-thread block.
// lane = e_l*4 + h  (16 edge slots x 4 heads) for BOTH logits and V-accum.
// Each lane accumulates p_e * V[src_e][h*32 + 0..31] into 32 private regs;
// one butterfly reduction over edge-lanes (xor 4,8,16,32) per node at the end.
// mode 0: out[N][128] = relu(concat agg + skip)   (skip incl. bias, from GEMM)
// mode 1: out[N][32]  = mean_h(agg) + skip
__global__ __launch_bounds__(256,4) void k_attn(
  const float* __restrict__ QKVS, const int* __restrict__ offs,
  const int* __restrict__ srcs, float* __restrict__ out, int mode, int n)
{
  int wv = threadIdx.x>>6, lane = threadIdx.x&63;
  int node = blockIdx.x*4 + wv;
  if(node >= n) return;
  int h = lane & 3;
  int e_l = lane >> 2;
  const float rs = 0.17677669529663687f;  // 1/sqrt(32)
  const float* qp = QKVS + (size_t)node*QKVS_STRIDE + h*32;
  float4 q[8];
  #pragma unroll
  for(int j=0;j<8;j++){
    float4 tq = *(const float4*)(qp + j*4);
    q[j] = make_float4(tq.x*rs, tq.y*rs, tq.z*rs, tq.w*rs);
  }
  int beg = offs[node], end = offs[node+1];
  float m = -__builtin_inff(), s = 0.f;
  float4 acc[8];
  #pragma unroll
  for(int j=0;j<8;j++) acc[j] = make_float4(0.f,0.f,0.f,0.f);

  for(int b0 = beg; b0 < end; b0 += 16){
    int idx = b0 + e_l;
    bool valid = idx < end;
    int sj = srcs[valid ? idx : beg];
    const float* row = QKVS + (size_t)sj*QKVS_STRIDE + h*32;
    // K chunk for this (edge, head)
    float4 kv[8];
    #pragma unroll
    for(int j=0;j<8;j++) kv[j] = *(const float4*)(row + 128 + j*4);
    float dot = 0.f;
    #pragma unroll
    for(int j=0;j<8;j++)
      dot += q[j].x*kv[j].x + q[j].y*kv[j].y + q[j].z*kv[j].z + q[j].w*kv[j].w;
    float logit = valid ? dot : -__builtin_inff();
    // V chunk (issue before the softmax shuffle chain; overlaps latency)
    float4 vv[8];
    #pragma unroll
    for(int j=0;j<8;j++) vv[j] = *(const float4*)(row + 256 + j*4);
    // per-head max over the 16 edge slots
    float bm = logit;
    bm = fmaxf(bm, __shfl_xor(bm,4));
    bm = fmaxf(bm, __shfl_xor(bm,8));
    bm = fmaxf(bm, __shfl_xor(bm,16));
    bm = fmaxf(bm, __shfl_xor(bm,32));
    float mn = fmaxf(m, bm);
    float r = __expf(m - mn);       // m=-inf -> 0
    float p = __expf(logit - mn);   // invalid lanes -> 0
    float ps = p;
    ps += __shfl_xor(ps,4); ps += __shfl_xor(ps,8); ps += __shfl_xor(ps,16); ps += __shfl_xor(ps,32);
    s = r*s + ps; m = mn;
    #pragma unroll
    for(int j=0;j<8;j++){
      acc[j].x = fmaf(acc[j].x, r, p*vv[j].x);
      acc[j].y = fmaf(acc[j].y, r, p*vv[j].y);
      acc[j].z = fmaf(acc[j].z, r, p*vv[j].z);
      acc[j].w = fmaf(acc[j].w, r, p*vv[j].w);
    }
  }
  // butterfly reduce over the 16 edge lanes (all lanes end with head-h sums)
  #pragma unroll
  for(int j=0;j<8;j++){
    acc[j].x += __shfl_xor(acc[j].x,4);  acc[j].y += __shfl_xor(acc[j].y,4);
    acc[j].z += __shfl_xor(acc[j].z,4);  acc[j].w += __shfl_xor(acc[j].w,4);
    acc[j].x += __shfl_xor(acc[j].x,8);  acc[j].y += __shfl_xor(acc[j].y,8);
    acc[j].z += __shfl_xor(acc[j].z,8);  acc[j].w += __shfl_xor(acc[j].w,8);
    acc[j].x += __shfl_xor(acc[j].x,16); acc[j].y += __shfl_xor(acc[j].y,16);
    acc[j].z += __shfl_xor(acc[j].z,16); acc[j].w += __shfl_xor(acc[j].w,16);
    acc[j].x += __shfl_xor(acc[j].x,32); acc[j].y += __shfl_xor(acc[j].y,32);
    acc[j].z += __shfl_xor(acc[j].z,32); acc[j].w += __shfl_xor(acc[j].w,32);
  }
  float inv = (s > 0.f) ? (1.f/s) : 0.f;   // s already per-head uniform
  if(mode == 0){
    if(e_l == 0){
      const float* sk = QKVS + (size_t)node*QKVS_STRIDE + 384 + h*32;
      float* op = out + (size_t)node*128 + h*32;
      #pragma unroll
      for(int j=0;j<8;j++){
        float4 sv = *(const float4*)(sk + j*4);
        float4 o;
        o.x = fmaxf(fmaf(acc[j].x, inv, sv.x), 0.f);
        o.y = fmaxf(fmaf(acc[j].y, inv, sv.y), 0.f);
        o.z = fmaxf(fmaf(acc[j].z, inv, sv.z), 0.f);
        o.w = fmaxf(fmaf(acc[j].w, inv, sv.w), 0.f);
        *(float4*)(op + j*4) = o;
      }
    }
  } else {
    float sc = inv*0.25f;
    #pragma unroll
    for(int j=0;j<8;j++){
      acc[j].x *= sc; acc[j].y *= sc; acc[j].z *= sc; acc[j].w *= sc;
      acc[j].x += __shfl_xor(acc[j].x,1); acc[j].y += __shfl_xor(acc[j].y,1);
      acc[j].z += __shfl_xor(acc[j].z,1); acc[j].w += __shfl_xor(acc[j].w,1);
      acc[j].x += __shfl_xor(acc[j].x,2); acc[j].y += __shfl_xor(acc[j].y,2);
      acc[j].z += __shfl_xor(acc[j].z,2); acc[j].w += __shfl_xor(acc[j].w,2);
    }
    if(lane == 0){
      const float* sk = QKVS + (size_t)node*QKVS_STRIDE + 384;
      float* op = out + (size_t)node*32;
      #pragma unroll
      for(int j=0;j<8;j++){
        float4 sv = *(const float4*)(sk + j*4);
        float4 o = make_float4(acc[j].x+sv.x, acc[j].y+sv.y, acc[j].z+sv.z, acc[j].w+sv.w);
        *(float4*)(op + j*4) = o;
      }
    }
  }
}

extern "C" void kernel_launch(void* const* d_in, const int* in_sizes, int n_in,
                              void* d_out, int out_size, void* d_ws, size_t ws_size,
                              hipStream_t stream) {
  const float* x = (const float*)d_in[0];
  const int* ei = (const int*)d_in[1];
  int n = in_sizes[0]/DIN;
  int E = in_sizes[1]/2;
  const int* esrc = ei;
  const int* edst = ei + E;

  char* w = (char*)d_ws;
  auto alloc = [&](size_t bytes)->char*{
    char* p = w; w += (bytes + 255) & ~(size_t)255; return p;
  };
  int* offs = (int*)alloc((size_t)(n+1)*4);
  int* deg  = (int*)alloc((size_t)n*4);
  int* cur  = (int*)alloc((size_t)n*4);
  int* part = (int*)alloc(256*4);
  int* srcs = (int*)alloc((size_t)E*4);
  float* qkvs = (float*)alloc((size_t)n*QKVS_STRIDE*4);
  float* h1 = (float*)alloc((size_t)n*128*4);
  float* h2 = (float*)alloc((size_t)n*128*4);

  int SB = (n+255)/256;  // 196 (<=256 required for 2-level scan)
  hipLaunchKernelGGL(k_zero, dim3((n+255)/256), dim3(256), 0, stream, deg, n);
  hipLaunchKernelGGL(k_zero, dim3((n+255)/256), dim3(256), 0, stream, cur, n);
  hipLaunchKernelGGL(k_count, dim3((E+255)/256), dim3(256), 0, stream, edst, deg, E);
  hipLaunchKernelGGL(k_scan1, dim3(SB), dim3(256), 0, stream, deg, offs, part, n);
  hipLaunchKernelGGL(k_scan2, dim3(1), dim3(256), 0, stream, part, SB);
  hipLaunchKernelGGL(k_scan3, dim3(SB), dim3(256), 0, stream, offs, part, n);
  hipLaunchKernelGGL(k_scatter, dim3((E+255)/256), dim3(256), 0, stream, esrc, edst, offs, cur, srcs, E);

  auto f = [&](int i)->const float*{ return (const float*)d_in[i]; };
  int RT = (n+63)/64;
  int AB = (n+3)/4;

  // layer 0
  hipLaunchKernelGGL(k_gemm, dim3(8, RT), dim3(256), 0, stream,
                     x, n, f(2),f(3),f(4),f(5),f(6),f(7),f(8),f(9), 128, qkvs);
  hipLaunchKernelGGL(k_attn, dim3(AB), dim3(256), 0, stream, qkvs, offs, srcs, h1, 0, n);
  // layer 1
  hipLaunchKernelGGL(k_gemm, dim3(8, RT), dim3(256), 0, stream,
                     h1, n, f(10),f(11),f(12),f(13),f(14),f(15),f(16),f(17), 128, qkvs);
  hipLaunchKernelGGL(k_attn, dim3(AB), dim3(256), 0, stream, qkvs, offs, srcs, h2, 0, n);
  // layer 2 (skip width 32, mean over heads)
  hipLaunchKernelGGL(k_gemm, dim3(8, RT), dim3(256), 0, stream,
                     h2, n, f(18),f(19),f(20),f(21),f(22),f(23),f(24),f(25), 32, qkvs);
  hipLaunchKernelGGL(k_attn, dim3(AB), dim3(256), 0, stream, qkvs, offs, srcs, (float*)d_out, 1, n);
}

// Round 3
// 1121.948 us; speedup vs baseline: 1.1406x; 1.1406x over previous
//
#include <hip/hip_runtime.h>
#include <cstdint>
#include <cstddef>

#define DIN 128   // feature width of all layer inputs (and Q/K/V width = H*DH)
#define QKVS_STRIDE 512

// ---------------- CSR build ----------------
__global__ void k_zero(int* __restrict__ a, int n){
  int i = blockIdx.x*blockDim.x + threadIdx.x;
  if(i<n) a[i]=0;
}

__global__ void k_count(const int* __restrict__ dst, int* __restrict__ deg, int E){
  int i = blockIdx.x*blockDim.x + threadIdx.x;
  if(i<E) atomicAdd(&deg[dst[i]], 1);
}

__global__ void k_scan1(const int* __restrict__ deg, int* __restrict__ offs,
                        int* __restrict__ part, int n){
  __shared__ int sm[256];
  int t = threadIdx.x; int g = blockIdx.x*256 + t;
  int v = (g<n)? deg[g] : 0;
  sm[t] = v;
  for(int o=1;o<256;o<<=1){
    __syncthreads();
    int x = (t>=o)? sm[t-o] : 0;
    __syncthreads();
    sm[t] += x;
  }
  __syncthreads();
  if(g<n) offs[g+1] = sm[t];
  if(t==255) part[blockIdx.x] = sm[255];
}

__global__ void k_scan2(int* __restrict__ part, int nb){
  __shared__ int sm[256];
  int t=threadIdx.x;
  int v = (t<nb)? part[t] : 0;
  sm[t]=v;
  for(int o=1;o<256;o<<=1){ __syncthreads(); int x=(t>=o)?sm[t-o]:0; __syncthreads(); sm[t]+=x; }
  __syncthreads();
  if(t<nb) part[t] = sm[t]-v;  // exclusive prefix of block totals
}

__global__ void k_scan3(int* __restrict__ offs, const int* __restrict__ part, int n){
  int t=threadIdx.x; int g=blockIdx.x*256+t;
  if(g<n) offs[g+1] += part[blockIdx.x];
  if(g==0) offs[0]=0;
}

__global__ void k_scatter(const int* __restrict__ src, const int* __restrict__ dst,
                          const int* __restrict__ offs, int* __restrict__ cur,
                          int* __restrict__ srcs, int E){
  int i=blockIdx.x*blockDim.x+threadIdx.x;
  if(i<E){
    int d = dst[i];
    int p = atomicAdd(&cur[d],1);
    srcs[offs[d]+p] = src[i];
  }
}

// ---------------- fused QKVS GEMM (fp32) ----------------
// out[N][512]: cols 0..127 = Q, 128..255 = K, 256..383 = V, 384.. = S (ws_cols wide)
// grid: (8, row_tiles): blockIdx.x -> mat = bx>>1 (0..3), col-tile = bx&1
__global__ __launch_bounds__(256,2) void k_gemm(
  const float* __restrict__ X, int nrows,
  const float* __restrict__ Wq, const float* __restrict__ bq,
  const float* __restrict__ Wk, const float* __restrict__ bk,
  const float* __restrict__ Wv, const float* __restrict__ bv,
  const float* __restrict__ Ws, const float* __restrict__ bs,
  int ws_cols, float* __restrict__ out)
{
  __shared__ float Xs[64][128];
  __shared__ float Wsh[128][64];
  int t = threadIdx.x;
  int mat = blockIdx.x >> 1, ct = blockIdx.x & 1;
  int wcols = (mat==3)? ws_cols : 128;
  int col0 = ct*64;
  if(col0 >= wcols) return;
  const float* W; const float* b;
  if(mat==0){W=Wq;b=bq;} else if(mat==1){W=Wk;b=bk;} else if(mat==2){W=Wv;b=bv;} else {W=Ws;b=bs;}
  int row0 = blockIdx.y*64;
  {
    int r = t>>5, c4 = (t&31)<<2;
    #pragma unroll
    for(int j=0;j<8;j++){
      int rr = r + (j<<3); int gr = row0+rr;
      float4 v = make_float4(0.f,0.f,0.f,0.f);
      if(gr < nrows) v = *(const float4*)(X + (size_t)gr*DIN + c4);
      *(float4*)&Xs[rr][c4] = v;
    }
    int k0 = t>>4, cc = (t&15)<<2;
    #pragma unroll
    for(int j=0;j<8;j++){
      int kk = k0 + (j<<4); int gc = col0 + cc;
      float4 v = make_float4(0.f,0.f,0.f,0.f);
      if(gc+3 < wcols) v = *(const float4*)(W + (size_t)kk*wcols + gc);
      *(float4*)&Wsh[kk][cc] = v;
    }
  }
  __syncthreads();
  int tr = t>>4, tc = t&15;
  int r0 = tr<<2, c0 = tc<<2;
  float acc[4][4];
  #pragma unroll
  for(int i=0;i<4;i++){ acc[i][0]=0.f; acc[i][1]=0.f; acc[i][2]=0.f; acc[i][3]=0.f; }
  #pragma unroll 8
  for(int k=0;k<128;k++){
    float4 w4 = *(const float4*)&Wsh[k][c0];
    #pragma unroll
    for(int i=0;i<4;i++){
      float x = Xs[r0+i][k];
      acc[i][0] += x*w4.x; acc[i][1] += x*w4.y; acc[i][2] += x*w4.z; acc[i][3] += x*w4.w;
    }
  }
  int cbase = col0 + c0;
  if(cbase+3 < wcols || wcols==128){
    float4 bb = *(const float4*)(b + cbase);
    #pragma unroll
    for(int i=0;i<4;i++){
      int gr = row0 + r0 + i;
      if(gr < nrows){
        float4 o = make_float4(acc[i][0]+bb.x, acc[i][1]+bb.y, acc[i][2]+bb.z, acc[i][3]+bb.w);
        *(float4*)(out + (size_t)gr*QKVS_STRIDE + mat*128 + cbase) = o;
      }
    }
  }
}

// ---------------- per-node attention (online softmax, CSR) ----------------
// one wave (64 lanes) per dst node; 4 waves / 256-thread block.
// lane = e_l*4 + h  (16 edge slots x 4 heads) for BOTH logits and V-accum.
// Per batch: issue all 8 V float4 loads FIRST (pinned live via asm), stream K
// into the dot, softmax via 4 shfl_xor, then consume V into 32 private regs.
// One butterfly reduction over edge-lanes per node at the end.
// mode 0: out[N][128] = relu(concat agg + skip)   (skip incl. bias, from GEMM)
// mode 1: out[N][32]  = mean_h(agg) + skip
__global__ __launch_bounds__(256,3) void k_attn(
  const float* __restrict__ QKVS, const int* __restrict__ offs,
  const int* __restrict__ srcs, float* __restrict__ out, int mode, int n)
{
  int wv = threadIdx.x>>6, lane = threadIdx.x&63;
  int node = blockIdx.x*4 + wv;
  if(node >= n) return;
  int h = lane & 3;
  int e_l = lane >> 2;
  const float rs = 0.17677669529663687f;  // 1/sqrt(32)
  const float* qp = QKVS + (size_t)node*QKVS_STRIDE + h*32;
  float4 q[8];
  #pragma unroll
  for(int j=0;j<8;j++){
    float4 tq = *(const float4*)(qp + j*4);
    q[j] = make_float4(tq.x*rs, tq.y*rs, tq.z*rs, tq.w*rs);
  }
  int beg = offs[node], end = offs[node+1];
  float m = -__builtin_inff(), s = 0.f;
  float4 acc[8];
  #pragma unroll
  for(int j=0;j<8;j++) acc[j] = make_float4(0.f,0.f,0.f,0.f);

  for(int b0 = beg; b0 < end; b0 += 16){
    int idx = b0 + e_l;
    bool valid = idx < end;
    int sj = srcs[valid ? idx : beg];
    const float* row = QKVS + (size_t)sj*QKVS_STRIDE + h*32;
    // V chunk first — pin live so these 8 loads stay in flight through
    // the dot + softmax window instead of being sunk to their use.
    float4 vv[8];
    #pragma unroll
    for(int j=0;j<8;j++) vv[j] = *(const float4*)(row + 256 + j*4);
    #pragma unroll
    for(int j=0;j<8;j++)
      asm volatile("" : "+v"(vv[j].x), "+v"(vv[j].y), "+v"(vv[j].z), "+v"(vv[j].w));
    // K streams into the dot (8 independent loads, consumed by FMAs)
    float dot = 0.f;
    #pragma unroll
    for(int j=0;j<8;j++){
      float4 kv = *(const float4*)(row + 128 + j*4);
      dot += q[j].x*kv.x + q[j].y*kv.y + q[j].z*kv.z + q[j].w*kv.w;
    }
    float logit = valid ? dot : -__builtin_inff();
    // per-head max over the 16 edge slots
    float bm = logit;
    bm = fmaxf(bm, __shfl_xor(bm,4));
    bm = fmaxf(bm, __shfl_xor(bm,8));
    bm = fmaxf(bm, __shfl_xor(bm,16));
    bm = fmaxf(bm, __shfl_xor(bm,32));
    float mn = fmaxf(m, bm);
    float r = __expf(m - mn);       // m=-inf -> 0
    float p = __expf(logit - mn);   // invalid lanes -> 0
    float ps = p;
    ps += __shfl_xor(ps,4); ps += __shfl_xor(ps,8); ps += __shfl_xor(ps,16); ps += __shfl_xor(ps,32);
    s = r*s + ps; m = mn;
    #pragma unroll
    for(int j=0;j<8;j++){
      acc[j].x = fmaf(acc[j].x, r, p*vv[j].x);
      acc[j].y = fmaf(acc[j].y, r, p*vv[j].y);
      acc[j].z = fmaf(acc[j].z, r, p*vv[j].z);
      acc[j].w = fmaf(acc[j].w, r, p*vv[j].w);
    }
  }
  // butterfly reduce over the 16 edge lanes (all lanes end with head-h sums)
  #pragma unroll
  for(int j=0;j<8;j++){
    acc[j].x += __shfl_xor(acc[j].x,4);  acc[j].y += __shfl_xor(acc[j].y,4);
    acc[j].z += __shfl_xor(acc[j].z,4);  acc[j].w += __shfl_xor(acc[j].w,4);
    acc[j].x += __shfl_xor(acc[j].x,8);  acc[j].y += __shfl_xor(acc[j].y,8);
    acc[j].z += __shfl_xor(acc[j].z,8);  acc[j].w += __shfl_xor(acc[j].w,8);
    acc[j].x += __shfl_xor(acc[j].x,16); acc[j].y += __shfl_xor(acc[j].y,16);
    acc[j].z += __shfl_xor(acc[j].z,16); acc[j].w += __shfl_xor(acc[j].w,16);
    acc[j].x += __shfl_xor(acc[j].x,32); acc[j].y += __shfl_xor(acc[j].y,32);
    acc[j].z += __shfl_xor(acc[j].z,32); acc[j].w += __shfl_xor(acc[j].w,32);
  }
  float inv = (s > 0.f) ? (1.f/s) : 0.f;   // s already per-head uniform
  if(mode == 0){
    if(e_l == 0){
      const float* sk = QKVS + (size_t)node*QKVS_STRIDE + 384 + h*32;
      float* op = out + (size_t)node*128 + h*32;
      #pragma unroll
      for(int j=0;j<8;j++){
        float4 sv = *(const float4*)(sk + j*4);
        float4 o;
        o.x = fmaxf(fmaf(acc[j].x, inv, sv.x), 0.f);
        o.y = fmaxf(fmaf(acc[j].y, inv, sv.y), 0.f);
        o.z = fmaxf(fmaf(acc[j].z, inv, sv.z), 0.f);
        o.w = fmaxf(fmaf(acc[j].w, inv, sv.w), 0.f);
        *(float4*)(op + j*4) = o;
      }
    }
  } else {
    float sc = inv*0.25f;
    #pragma unroll
    for(int j=0;j<8;j++){
      acc[j].x *= sc; acc[j].y *= sc; acc[j].z *= sc; acc[j].w *= sc;
      acc[j].x += __shfl_xor(acc[j].x,1); acc[j].y += __shfl_xor(acc[j].y,1);
      acc[j].z += __shfl_xor(acc[j].z,1); acc[j].w += __shfl_xor(acc[j].w,1);
      acc[j].x += __shfl_xor(acc[j].x,2); acc[j].y += __shfl_xor(acc[j].y,2);
      acc[j].z += __shfl_xor(acc[j].z,2); acc[j].w += __shfl_xor(acc[j].w,2);
    }
    if(lane == 0){
      const float* sk = QKVS + (size_t)node*QKVS_STRIDE + 384;
      float* op = out + (size_t)node*32;
      #pragma unroll
      for(int j=0;j<8;j++){
        float4 sv = *(const float4*)(sk + j*4);
        float4 o = make_float4(acc[j].x+sv.x, acc[j].y+sv.y, acc[j].z+sv.z, acc[j].w+sv.w);
        *(float4*)(op + j*4) = o;
      }
    }
  }
}

extern "C" void kernel_launch(void* const* d_in, const int* in_sizes, int n_in,
                              void* d_out, int out_size, void* d_ws, size_t ws_size,
                              hipStream_t stream) {
  const float* x = (const float*)d_in[0];
  const int* ei = (const int*)d_in[1];
  int n = in_sizes[0]/DIN;
  int E = in_sizes[1]/2;
  const int* esrc = ei;
  const int* edst = ei + E;

  char* w = (char*)d_ws;
  auto alloc = [&](size_t bytes)->char*{
    char* p = w; w += (bytes + 255) & ~(size_t)255; return p;
  };
  int* offs = (int*)alloc((size_t)(n+1)*4);
  int* deg  = (int*)alloc((size_t)n*4);
  int* cur  = (int*)alloc((size_t)n*4);
  int* part = (int*)alloc(256*4);
  int* srcs = (int*)alloc((size_t)E*4);
  float* qkvs = (float*)alloc((size_t)n*QKVS_STRIDE*4);
  float* h1 = (float*)alloc((size_t)n*128*4);
  float* h2 = (float*)alloc((size_t)n*128*4);

  int SB = (n+255)/256;  // 196 (<=256 required for 2-level scan)
  hipLaunchKernelGGL(k_zero, dim3((n+255)/256), dim3(256), 0, stream, deg, n);
  hipLaunchKernelGGL(k_zero, dim3((n+255)/256), dim3(256), 0, stream, cur, n);
  hipLaunchKernelGGL(k_count, dim3((E+255)/256), dim3(256), 0, stream, edst, deg, E);
  hipLaunchKernelGGL(k_scan1, dim3(SB), dim3(256), 0, stream, deg, offs, part, n);
  hipLaunchKernelGGL(k_scan2, dim3(1), dim3(256), 0, stream, part, SB);
  hipLaunchKernelGGL(k_scan3, dim3(SB), dim3(256), 0, stream, offs, part, n);
  hipLaunchKernelGGL(k_scatter, dim3((E+255)/256), dim3(256), 0, stream, esrc, edst, offs, cur, srcs, E);

  auto f = [&](int i)->const float*{ return (const float*)d_in[i]; };
  int RT = (n+63)/64;
  int AB = (n+3)/4;

  // layer 0
  hipLaunchKernelGGL(k_gemm, dim3(8, RT), dim3(256), 0, stream,
                     x, n, f(2),f(3),f(4),f(5),f(6),f(7),f(8),f(9), 128, qkvs);
  hipLaunchKernelGGL(k_attn, dim3(AB), dim3(256), 0, stream, qkvs, offs, srcs, h1, 0, n);
  // layer 1
  hipLaunchKernelGGL(k_gemm, dim3(8, RT), dim3(256), 0, stream,
                     h1, n, f(10),f(11),f(12),f(13),f(14),f(15),f(16),f(17), 128, qkvs);
  hipLaunchKernelGGL(k_attn, dim3(AB), dim3(256), 0, stream, qkvs, offs, srcs, h2, 0, n);
  // layer 2 (skip width 32, mean over heads)
  hipLaunchKernelGGL(k_gemm, dim3(8, RT), dim3(256), 0, stream,
                     h2, n, f(18),f(19),f(20),f(21),f(22),f(23),f(24),f(25), 32, qkvs);
  hipLaunchKernelGGL(k_attn, dim3(AB), dim3(256), 0, stream, qkvs, offs, srcs, (float*)d_out, 1, n);
}

// Round 4
// 874.840 us; speedup vs baseline: 1.4627x; 1.2825x over previous
//
#include <hip/hip_runtime.h>
#include <cstdint>
#include <cstddef>

#define DIN 128        // feature width of all layer inputs (and Q/K/V width = H*DH)
#define ROW_BYTES 1536 // per-node row: Q fp32 [0,512) | K bf16 [512,768) | V bf16 [768,1024) | S fp32 [1024,1536)

// ---------------- CSR build ----------------
__global__ void k_zero(int* __restrict__ a, int n){
  int i = blockIdx.x*blockDim.x + threadIdx.x;
  if(i<n) a[i]=0;
}

__global__ void k_count(const int* __restrict__ dst, int* __restrict__ deg, int E){
  int i = blockIdx.x*blockDim.x + threadIdx.x;
  if(i<E) atomicAdd(&deg[dst[i]], 1);
}

__global__ void k_scan1(const int* __restrict__ deg, int* __restrict__ offs,
                        int* __restrict__ part, int n){
  __shared__ int sm[256];
  int t = threadIdx.x; int g = blockIdx.x*256 + t;
  int v = (g<n)? deg[g] : 0;
  sm[t] = v;
  for(int o=1;o<256;o<<=1){
    __syncthreads();
    int x = (t>=o)? sm[t-o] : 0;
    __syncthreads();
    sm[t] += x;
  }
  __syncthreads();
  if(g<n) offs[g+1] = sm[t];
  if(t==255) part[blockIdx.x] = sm[255];
}

__global__ void k_scan2(int* __restrict__ part, int nb){
  __shared__ int sm[256];
  int t=threadIdx.x;
  int v = (t<nb)? part[t] : 0;
  sm[t]=v;
  for(int o=1;o<256;o<<=1){ __syncthreads(); int x=(t>=o)?sm[t-o]:0; __syncthreads(); sm[t]+=x; }
  __syncthreads();
  if(t<nb) part[t] = sm[t]-v;  // exclusive prefix of block totals
}

__global__ void k_scan3(int* __restrict__ offs, const int* __restrict__ part, int n){
  int t=threadIdx.x; int g=blockIdx.x*256+t;
  if(g<n) offs[g+1] += part[blockIdx.x];
  if(g==0) offs[0]=0;
}

__global__ void k_scatter(const int* __restrict__ src, const int* __restrict__ dst,
                          const int* __restrict__ offs, int* __restrict__ cur,
                          int* __restrict__ srcs, int E){
  int i=blockIdx.x*blockDim.x+threadIdx.x;
  if(i<E){
    int d = dst[i];
    int p = atomicAdd(&cur[d],1);
    srcs[offs[d]+p] = src[i];
  }
}

// bf16 helpers (bf16 = top 16 bits of fp32; RNE pack)
__device__ inline unsigned f2bf(float x){
  unsigned u = __float_as_uint(x);
  return (u + 0x7FFFu + ((u>>16)&1u)) >> 16;
}
__device__ inline unsigned pack2(float a, float b){ return f2bf(a) | (f2bf(b)<<16); }
__device__ inline float bflo(unsigned w){ return __uint_as_float(w<<16); }
__device__ inline float bfhi(unsigned w){ return __uint_as_float(w & 0xFFFF0000u); }

// ---------------- fused QKVS GEMM (fp32 math; K,V stored bf16) ----------------
// grid: (8, row_tiles): blockIdx.x -> mat = bx>>1 (0..3), col-tile = bx&1
__global__ __launch_bounds__(256,2) void k_gemm(
  const float* __restrict__ X, int nrows,
  const float* __restrict__ Wq, const float* __restrict__ bq,
  const float* __restrict__ Wk, const float* __restrict__ bk,
  const float* __restrict__ Wv, const float* __restrict__ bv,
  const float* __restrict__ Ws, const float* __restrict__ bs,
  int ws_cols, char* __restrict__ out)
{
  __shared__ float Xs[64][128];
  __shared__ float Wsh[128][64];
  int t = threadIdx.x;
  int mat = blockIdx.x >> 1, ct = blockIdx.x & 1;
  int wcols = (mat==3)? ws_cols : 128;
  int col0 = ct*64;
  if(col0 >= wcols) return;
  const float* W; const float* b;
  if(mat==0){W=Wq;b=bq;} else if(mat==1){W=Wk;b=bk;} else if(mat==2){W=Wv;b=bv;} else {W=Ws;b=bs;}
  int row0 = blockIdx.y*64;
  {
    int r = t>>5, c4 = (t&31)<<2;
    #pragma unroll
    for(int j=0;j<8;j++){
      int rr = r + (j<<3); int gr = row0+rr;
      float4 v = make_float4(0.f,0.f,0.f,0.f);
      if(gr < nrows) v = *(const float4*)(X + (size_t)gr*DIN + c4);
      *(float4*)&Xs[rr][c4] = v;
    }
    int k0 = t>>4, cc = (t&15)<<2;
    #pragma unroll
    for(int j=0;j<8;j++){
      int kk = k0 + (j<<4); int gc = col0 + cc;
      float4 v = make_float4(0.f,0.f,0.f,0.f);
      if(gc+3 < wcols) v = *(const float4*)(W + (size_t)kk*wcols + gc);
      *(float4*)&Wsh[kk][cc] = v;
    }
  }
  __syncthreads();
  int tr = t>>4, tc = t&15;
  int r0 = tr<<2, c0 = tc<<2;
  float acc[4][4];
  #pragma unroll
  for(int i=0;i<4;i++){ acc[i][0]=0.f; acc[i][1]=0.f; acc[i][2]=0.f; acc[i][3]=0.f; }
  #pragma unroll 8
  for(int k=0;k<128;k++){
    float4 w4 = *(const float4*)&Wsh[k][c0];
    #pragma unroll
    for(int i=0;i<4;i++){
      float x = Xs[r0+i][k];
      acc[i][0] += x*w4.x; acc[i][1] += x*w4.y; acc[i][2] += x*w4.z; acc[i][3] += x*w4.w;
    }
  }
  int cbase = col0 + c0;
  if(cbase+3 < wcols || wcols==128){
    float4 bb = *(const float4*)(b + cbase);
    #pragma unroll
    for(int i=0;i<4;i++){
      int gr = row0 + r0 + i;
      if(gr < nrows){
        float o0=acc[i][0]+bb.x, o1=acc[i][1]+bb.y, o2=acc[i][2]+bb.z, o3=acc[i][3]+bb.w;
        char* rowp = out + (size_t)gr*ROW_BYTES;
        if(mat==0){
          *(float4*)(rowp + cbase*4) = make_float4(o0,o1,o2,o3);
        } else if(mat==3){
          *(float4*)(rowp + 1024 + cbase*4) = make_float4(o0,o1,o2,o3);
        } else {
          uint2 pk = make_uint2(pack2(o0,o1), pack2(o2,o3));
          *(uint2*)(rowp + ((mat==1)?512:768) + cbase*2) = pk;
        }
      }
    }
  }
}

// ---------------- per-node attention (online softmax, CSR, bf16 K/V) ----------------
// one wave (64 lanes) per dst node; 4 waves / 256-thread block.
// lane = e_l*4 + h (16 edge slots x 4 heads) for BOTH logits and V-accum.
// Per batch: issue 4x uint4 V loads first (pinned), stream 4x uint4 K into the
// dot, softmax via shfl_xor, consume V into 32 private regs. One butterfly
// reduction over edge lanes per node at the end.
// mode 0: out[N][128] = relu(concat agg + skip);  mode 1: out[N][32] = mean_h(agg)+skip
__global__ __launch_bounds__(256,4) void k_attn(
  const char* __restrict__ QKVS, const int* __restrict__ offs,
  const int* __restrict__ srcs, float* __restrict__ out, int mode, int n)
{
  int wv = threadIdx.x>>6, lane = threadIdx.x&63;
  int node = blockIdx.x*4 + wv;
  if(node >= n) return;
  int h = lane & 3;
  int e_l = lane >> 2;
  const float rs = 0.17677669529663687f;  // 1/sqrt(32)
  const float* qp = (const float*)(QKVS + (size_t)node*ROW_BYTES) + h*32;
  float4 q[8];
  #pragma unroll
  for(int j=0;j<8;j++){
    float4 tq = *(const float4*)(qp + j*4);
    q[j] = make_float4(tq.x*rs, tq.y*rs, tq.z*rs, tq.w*rs);
  }
  int beg = offs[node], end = offs[node+1];
  float m = -__builtin_inff(), s = 0.f;
  float4 acc[8];
  #pragma unroll
  for(int j=0;j<8;j++) acc[j] = make_float4(0.f,0.f,0.f,0.f);

  for(int b0 = beg; b0 < end; b0 += 16){
    int idx = b0 + e_l;
    bool valid = idx < end;
    int sj = srcs[valid ? idx : beg];
    const char* row = QKVS + (size_t)sj*ROW_BYTES;
    // V chunk first (4x 16B = 32 bf16), pinned live across dot+softmax
    uint4 vw[4];
    const uint4* vp = (const uint4*)(row + 768 + h*64);
    #pragma unroll
    for(int j=0;j<4;j++) vw[j] = vp[j];
    #pragma unroll
    for(int j=0;j<4;j++)
      asm volatile("" : "+v"(vw[j].x), "+v"(vw[j].y), "+v"(vw[j].z), "+v"(vw[j].w));
    // K streams into the dot
    const uint4* kp = (const uint4*)(row + 512 + h*64);
    float dot = 0.f;
    #pragma unroll
    for(int j=0;j<4;j++){
      uint4 kw = kp[j];
      float4 qa = q[2*j], qb = q[2*j+1];
      dot += qa.x*bflo(kw.x) + qa.y*bfhi(kw.x) + qa.z*bflo(kw.y) + qa.w*bfhi(kw.y);
      dot += qb.x*bflo(kw.z) + qb.y*bfhi(kw.z) + qb.z*bflo(kw.w) + qb.w*bfhi(kw.w);
    }
    float logit = valid ? dot : -__builtin_inff();
    // per-head max over the 16 edge slots
    float bm = logit;
    bm = fmaxf(bm, __shfl_xor(bm,4));
    bm = fmaxf(bm, __shfl_xor(bm,8));
    bm = fmaxf(bm, __shfl_xor(bm,16));
    bm = fmaxf(bm, __shfl_xor(bm,32));
    float mn = fmaxf(m, bm);
    float r = __expf(m - mn);       // m=-inf -> 0
    float p = __expf(logit - mn);   // invalid lanes -> 0
    float ps = p;
    ps += __shfl_xor(ps,4); ps += __shfl_xor(ps,8); ps += __shfl_xor(ps,16); ps += __shfl_xor(ps,32);
    s = r*s + ps; m = mn;
    #pragma unroll
    for(int j=0;j<4;j++){
      uint4 w = vw[j];
      float4 a0 = acc[2*j], a1 = acc[2*j+1];
      a0.x = fmaf(a0.x, r, p*bflo(w.x)); a0.y = fmaf(a0.y, r, p*bfhi(w.x));
      a0.z = fmaf(a0.z, r, p*bflo(w.y)); a0.w = fmaf(a0.w, r, p*bfhi(w.y));
      a1.x = fmaf(a1.x, r, p*bflo(w.z)); a1.y = fmaf(a1.y, r, p*bfhi(w.z));
      a1.z = fmaf(a1.z, r, p*bflo(w.w)); a1.w = fmaf(a1.w, r, p*bfhi(w.w));
      acc[2*j] = a0; acc[2*j+1] = a1;
    }
  }
  // butterfly reduce over the 16 edge lanes (all lanes end with head-h sums)
  #pragma unroll
  for(int j=0;j<8;j++){
    acc[j].x += __shfl_xor(acc[j].x,4);  acc[j].y += __shfl_xor(acc[j].y,4);
    acc[j].z += __shfl_xor(acc[j].z,4);  acc[j].w += __shfl_xor(acc[j].w,4);
    acc[j].x += __shfl_xor(acc[j].x,8);  acc[j].y += __shfl_xor(acc[j].y,8);
    acc[j].z += __shfl_xor(acc[j].z,8);  acc[j].w += __shfl_xor(acc[j].w,8);
    acc[j].x += __shfl_xor(acc[j].x,16); acc[j].y += __shfl_xor(acc[j].y,16);
    acc[j].z += __shfl_xor(acc[j].z,16); acc[j].w += __shfl_xor(acc[j].w,16);
    acc[j].x += __shfl_xor(acc[j].x,32); acc[j].y += __shfl_xor(acc[j].y,32);
    acc[j].z += __shfl_xor(acc[j].z,32); acc[j].w += __shfl_xor(acc[j].w,32);
  }
  float inv = (s > 0.f) ? (1.f/s) : 0.f;   // s already per-head uniform
  if(mode == 0){
    if(e_l == 0){
      const float* sk = (const float*)(QKVS + (size_t)node*ROW_BYTES + 1024) + h*32;
      float* op = out + (size_t)node*128 + h*32;
      #pragma unroll
      for(int j=0;j<8;j++){
        float4 sv = *(const float4*)(sk + j*4);
        float4 o;
        o.x = fmaxf(fmaf(acc[j].x, inv, sv.x), 0.f);
        o.y = fmaxf(fmaf(acc[j].y, inv, sv.y), 0.f);
        o.z = fmaxf(fmaf(acc[j].z, inv, sv.z), 0.f);
        o.w = fmaxf(fmaf(acc[j].w, inv, sv.w), 0.f);
        *(float4*)(op + j*4) = o;
      }
    }
  } else {
    float sc = inv*0.25f;
    #pragma unroll
    for(int j=0;j<8;j++){
      acc[j].x *= sc; acc[j].y *= sc; acc[j].z *= sc; acc[j].w *= sc;
      acc[j].x += __shfl_xor(acc[j].x,1); acc[j].y += __shfl_xor(acc[j].y,1);
      acc[j].z += __shfl_xor(acc[j].z,1); acc[j].w += __shfl_xor(acc[j].w,1);
      acc[j].x += __shfl_xor(acc[j].x,2); acc[j].y += __shfl_xor(acc[j].y,2);
      acc[j].z += __shfl_xor(acc[j].z,2); acc[j].w += __shfl_xor(acc[j].w,2);
    }
    if(lane == 0){
      const float* sk = (const float*)(QKVS + (size_t)node*ROW_BYTES + 1024);
      float* op = out + (size_t)node*32;
      #pragma unroll
      for(int j=0;j<8;j++){
        float4 sv = *(const float4*)(sk + j*4);
        float4 o = make_float4(acc[j].x+sv.x, acc[j].y+sv.y, acc[j].z+sv.z, acc[j].w+sv.w);
        *(float4*)(op + j*4) = o;
      }
    }
  }
}

extern "C" void kernel_launch(void* const* d_in, const int* in_sizes, int n_in,
                              void* d_out, int out_size, void* d_ws, size_t ws_size,
                              hipStream_t stream) {
  const float* x = (const float*)d_in[0];
  const int* ei = (const int*)d_in[1];
  int n = in_sizes[0]/DIN;
  int E = in_sizes[1]/2;
  const int* esrc = ei;
  const int* edst = ei + E;

  char* w = (char*)d_ws;
  auto alloc = [&](size_t bytes)->char*{
    char* p = w; w += (bytes + 255) & ~(size_t)255; return p;
  };
  int* offs = (int*)alloc((size_t)(n+1)*4);
  int* deg  = (int*)alloc((size_t)n*4);
  int* cur  = (int*)alloc((size_t)n*4);
  int* part = (int*)alloc(256*4);
  int* srcs = (int*)alloc((size_t)E*4);
  char* qkvs = alloc((size_t)n*ROW_BYTES);
  float* h1 = (float*)alloc((size_t)n*128*4);
  float* h2 = (float*)alloc((size_t)n*128*4);

  int SB = (n+255)/256;  // 196 (<=256 required for 2-level scan)
  hipLaunchKernelGGL(k_zero, dim3((n+255)/256), dim3(256), 0, stream, deg, n);
  hipLaunchKernelGGL(k_zero, dim3((n+255)/256), dim3(256), 0, stream, cur, n);
  hipLaunchKernelGGL(k_count, dim3((E+255)/256), dim3(256), 0, stream, edst, deg, E);
  hipLaunchKernelGGL(k_scan1, dim3(SB), dim3(256), 0, stream, deg, offs, part, n);
  hipLaunchKernelGGL(k_scan2, dim3(1), dim3(256), 0, stream, part, SB);
  hipLaunchKernelGGL(k_scan3, dim3(SB), dim3(256), 0, stream, offs, part, n);
  hipLaunchKernelGGL(k_scatter, dim3((E+255)/256), dim3(256), 0, stream, esrc, edst, offs, cur, srcs, E);

  auto f = [&](int i)->const float*{ return (const float*)d_in[i]; };
  int RT = (n+63)/64;
  int AB = (n+3)/4;

  // layer 0
  hipLaunchKernelGGL(k_gemm, dim3(8, RT), dim3(256), 0, stream,
                     x, n, f(2),f(3),f(4),f(5),f(6),f(7),f(8),f(9), 128, qkvs);
  hipLaunchKernelGGL(k_attn, dim3(AB), dim3(256), 0, stream, qkvs, offs, srcs, h1, 0, n);
  // layer 1
  hipLaunchKernelGGL(k_gemm, dim3(8, RT), dim3(256), 0, stream,
                     h1, n, f(10),f(11),f(12),f(13),f(14),f(15),f(16),f(17), 128, qkvs);
  hipLaunchKernelGGL(k_attn, dim3(AB), dim3(256), 0, stream, qkvs, offs, srcs, h2, 0, n);
  // layer 2 (skip width 32, mean over heads)
  hipLaunchKernelGGL(k_gemm, dim3(8, RT), dim3(256), 0, stream,
                     h2, n, f(18),f(19),f(20),f(21),f(22),f(23),f(24),f(25), 32, qkvs);
  hipLaunchKernelGGL(k_attn, dim3(AB), dim3(256), 0, stream, qkvs, offs, srcs, (float*)d_out, 1, n);
}

// Round 5
// 639.683 us; speedup vs baseline: 2.0004x; 1.3676x over previous
//
#include <hip/hip_runtime.h>
#include <cstdint>
#include <cstddef>

#define DIN 128        // feature width of all layer inputs (and Q/K/V width = H*DH)
#define ROW_BYTES 1536 // per-node row: Q fp32 [0,512) | K bf16 [512,768) | V bf16 [768,1024) | S fp32 [1024,1536)

typedef __attribute__((ext_vector_type(8))) short short8v;
typedef __attribute__((ext_vector_type(4))) float float4v;

// ---------------- CSR build ----------------
__global__ void k_zero(int* __restrict__ a, int n){
  int i = blockIdx.x*blockDim.x + threadIdx.x;
  if(i<n) a[i]=0;
}

__global__ void k_count(const int* __restrict__ dst, int* __restrict__ deg, int E){
  int i = blockIdx.x*blockDim.x + threadIdx.x;
  if(i<E) atomicAdd(&deg[dst[i]], 1);
}

__global__ void k_scan1(const int* __restrict__ deg, int* __restrict__ offs,
                        int* __restrict__ part, int n){
  __shared__ int sm[256];
  int t = threadIdx.x; int g = blockIdx.x*256 + t;
  int v = (g<n)? deg[g] : 0;
  sm[t] = v;
  for(int o=1;o<256;o<<=1){
    __syncthreads();
    int x = (t>=o)? sm[t-o] : 0;
    __syncthreads();
    sm[t] += x;
  }
  __syncthreads();
  if(g<n) offs[g+1] = sm[t];
  if(t==255) part[blockIdx.x] = sm[255];
}

__global__ void k_scan2(int* __restrict__ part, int nb){
  __shared__ int sm[256];
  int t=threadIdx.x;
  int v = (t<nb)? part[t] : 0;
  sm[t]=v;
  for(int o=1;o<256;o<<=1){ __syncthreads(); int x=(t>=o)?sm[t-o]:0; __syncthreads(); sm[t]+=x; }
  __syncthreads();
  if(t<nb) part[t] = sm[t]-v;  // exclusive prefix of block totals
}

__global__ void k_scan3(int* __restrict__ offs, const int* __restrict__ part, int n){
  int t=threadIdx.x; int g=blockIdx.x*256+t;
  if(g<n) offs[g+1] += part[blockIdx.x];
  if(g==0) offs[0]=0;
}

__global__ void k_scatter(const int* __restrict__ src, const int* __restrict__ dst,
                          const int* __restrict__ offs, int* __restrict__ cur,
                          int* __restrict__ srcs, int E){
  int i=blockIdx.x*blockDim.x+threadIdx.x;
  if(i<E){
    int d = dst[i];
    int p = atomicAdd(&cur[d],1);
    srcs[offs[d]+p] = src[i];
  }
}

// bf16 helpers (bf16 = top 16 bits of fp32; RNE pack)
__device__ inline unsigned f2bf(float x){
  unsigned u = __float_as_uint(x);
  return (u + 0x7FFFu + ((u>>16)&1u)) >> 16;
}
__device__ inline unsigned pack2(float a, float b){ return f2bf(a) | (f2bf(b)<<16); }
__device__ inline float bflo(unsigned w){ return __uint_as_float(w<<16); }
__device__ inline float bfhi(unsigned w){ return __uint_as_float(w & 0xFFFF0000u); }

// ---------------- weight prep: fp32 [din][dout] -> bf16 transposed [dout][din] ----------------
// 12 mats, slot i at wt + i*16384 elements. i==11 is Ws2 (dout=32).
__global__ void k_wt(
  const float* __restrict__ W0, const float* __restrict__ W1, const float* __restrict__ W2,
  const float* __restrict__ W3, const float* __restrict__ W4, const float* __restrict__ W5,
  const float* __restrict__ W6, const float* __restrict__ W7, const float* __restrict__ W8,
  const float* __restrict__ W9, const float* __restrict__ W10, const float* __restrict__ W11,
  unsigned short* __restrict__ wt)
{
  int i = blockIdx.y;
  int e = blockIdx.x*256 + threadIdx.x;
  int dout = (i==11)? 32 : 128;
  if(e >= dout*128) return;
  const float* W;
  switch(i){
    case 0: W=W0; break; case 1: W=W1; break; case 2: W=W2; break; case 3: W=W3; break;
    case 4: W=W4; break; case 5: W=W5; break; case 6: W=W6; break; case 7: W=W7; break;
    case 8: W=W8; break; case 9: W=W9; break; case 10: W=W10; break; default: W=W11; break;
  }
  int c = e % dout, k = e / dout;
  wt[i*16384 + c*128 + k] = (unsigned short)f2bf(W[(size_t)k*dout + c]);
}

// ---------------- fused QKVS GEMM (bf16 MFMA, fp32 accum) ----------------
// grid: (8, row_tiles): blockIdx.x -> mat = bx>>1 (0..3), col-tile = bx&1.
// Block: 64 rows x 64 cols, K=128 staged entirely in LDS (one barrier).
// 4 waves; wave w owns cols [w*16, w*16+16). Per wave: 16 MFMA 16x16x32.
// LDS rows padded to 136 bf16 (272B = 68 dwords -> +4 banks/row -> ~2-way, free).
__global__ __launch_bounds__(256,4) void k_gemm(
  const float* __restrict__ X, int nrows,
  const unsigned short* __restrict__ Wt,   // this layer's 4 mats, mat m at +m*16384
  const float* __restrict__ bq, const float* __restrict__ bk,
  const float* __restrict__ bv, const float* __restrict__ bs,
  int ws_cols, char* __restrict__ out)
{
  __shared__ unsigned short Xs[64][136];
  __shared__ unsigned short Wsh[64][136];
  int t = threadIdx.x;
  int mat = blockIdx.x >> 1, ct = blockIdx.x & 1;
  int wcols = (mat==3)? ws_cols : 128;
  int col0 = ct*64;
  if(col0 >= wcols) return;
  const float* bias = (mat==0)?bq:(mat==1)?bk:(mat==2)?bv:bs;
  const unsigned short* Wm = Wt + mat*16384;
  int row0 = blockIdx.y*64;
  // ---- stage X (fp32 -> bf16) and W (bf16 copy) ----
  {
    int r = t>>2, kb = (t&3)*32;           // 64 rows x 4 thread-chunks of 32 k
    int gr = row0 + r;
    if(gr < nrows){
      const float* xp = X + (size_t)gr*DIN + kb;
      #pragma unroll
      for(int j=0;j<4;j++){
        float4 fa = *(const float4*)(xp + j*8);
        float4 fb = *(const float4*)(xp + j*8 + 4);
        uint4 pk = make_uint4(pack2(fa.x,fa.y), pack2(fa.z,fa.w),
                              pack2(fb.x,fb.y), pack2(fb.z,fb.w));
        *(uint4*)&Xs[r][kb + j*8] = pk;
      }
    } else {
      uint4 z = make_uint4(0,0,0,0);
      #pragma unroll
      for(int j=0;j<4;j++) *(uint4*)&Xs[r][kb + j*8] = z;
    }
    int c = r;                              // 64 cols x 4 chunks of 32 k
    int gc = col0 + c;
    if(gc < wcols){
      const unsigned short* wp = Wm + (size_t)gc*128 + kb;
      #pragma unroll
      for(int j=0;j<4;j++)
        *(uint4*)&Wsh[c][kb + j*8] = *(const uint4*)(wp + j*8);
    } else {
      uint4 z = make_uint4(0,0,0,0);
      #pragma unroll
      for(int j=0;j<4;j++) *(uint4*)&Wsh[c][kb + j*8] = z;
    }
  }
  __syncthreads();
  // ---- MFMA: wave w -> col slice; 4 m-tiles of 16 rows ----
  int wv = t>>6, l = t&63;
  int lr = l & 15, lk = (l>>4)*8;
  float4v acc[4];
  #pragma unroll
  for(int mt=0;mt<4;mt++) acc[mt] = (float4v){0.f,0.f,0.f,0.f};
  #pragma unroll
  for(int kk=0;kk<4;kk++){
    short8v b = *(const short8v*)&Wsh[wv*16 + lr][kk*32 + lk];
    #pragma unroll
    for(int mt=0;mt<4;mt++){
      short8v a = *(const short8v*)&Xs[mt*16 + lr][kk*32 + lk];
      acc[mt] = __builtin_amdgcn_mfma_f32_16x16x32_bf16(a, b, acc[mt], 0, 0, 0);
    }
  }
  // ---- epilogue: bias + store (Q,S fp32; K,V bf16) ----
  int col = col0 + wv*16 + lr;
  bool cok = col < wcols;
  float bcol = cok ? bias[col] : 0.f;
  int rb = row0 + (l>>4)*4;
  #pragma unroll
  for(int mt=0;mt<4;mt++){
    #pragma unroll
    for(int j=0;j<4;j++){
      int r = rb + mt*16 + j;
      if(r < nrows && cok){
        float val = acc[mt][j] + bcol;
        char* rowp = out + (size_t)r*ROW_BYTES;
        if(mat==0)      *(float*)(rowp + col*4) = val;
        else if(mat==1) *(unsigned short*)(rowp + 512 + col*2) = (unsigned short)f2bf(val);
        else if(mat==2) *(unsigned short*)(rowp + 768 + col*2) = (unsigned short)f2bf(val);
        else            *(float*)(rowp + 1024 + col*4) = val;
      }
    }
  }
}

// ---------------- per-node attention (online softmax, CSR, bf16 K/V) ----------------
__global__ __launch_bounds__(256,4) void k_attn(
  const char* __restrict__ QKVS, const int* __restrict__ offs,
  const int* __restrict__ srcs, float* __restrict__ out, int mode, int n)
{
  int wv = threadIdx.x>>6, lane = threadIdx.x&63;
  int node = blockIdx.x*4 + wv;
  if(node >= n) return;
  int h = lane & 3;
  int e_l = lane >> 2;
  const float rs = 0.17677669529663687f;  // 1/sqrt(32)
  const float* qp = (const float*)(QKVS + (size_t)node*ROW_BYTES) + h*32;
  float4 q[8];
  #pragma unroll
  for(int j=0;j<8;j++){
    float4 tq = *(const float4*)(qp + j*4);
    q[j] = make_float4(tq.x*rs, tq.y*rs, tq.z*rs, tq.w*rs);
  }
  int beg = offs[node], end = offs[node+1];
  float m = -__builtin_inff(), s = 0.f;
  float4 acc[8];
  #pragma unroll
  for(int j=0;j<8;j++) acc[j] = make_float4(0.f,0.f,0.f,0.f);

  for(int b0 = beg; b0 < end; b0 += 16){
    int idx = b0 + e_l;
    bool valid = idx < end;
    int sj = srcs[valid ? idx : beg];
    const char* row = QKVS + (size_t)sj*ROW_BYTES;
    // V chunk first (4x 16B = 32 bf16), pinned live across dot+softmax
    uint4 vw[4];
    const uint4* vp = (const uint4*)(row + 768 + h*64);
    #pragma unroll
    for(int j=0;j<4;j++) vw[j] = vp[j];
    #pragma unroll
    for(int j=0;j<4;j++)
      asm volatile("" : "+v"(vw[j].x), "+v"(vw[j].y), "+v"(vw[j].z), "+v"(vw[j].w));
    // K streams into the dot
    const uint4* kp = (const uint4*)(row + 512 + h*64);
    float dot = 0.f;
    #pragma unroll
    for(int j=0;j<4;j++){
      uint4 kw = kp[j];
      float4 qa = q[2*j], qb = q[2*j+1];
      dot += qa.x*bflo(kw.x) + qa.y*bfhi(kw.x) + qa.z*bflo(kw.y) + qa.w*bfhi(kw.y);
      dot += qb.x*bflo(kw.z) + qb.y*bfhi(kw.z) + qb.z*bflo(kw.w) + qb.w*bfhi(kw.w);
    }
    float logit = valid ? dot : -__builtin_inff();
    float bm = logit;
    bm = fmaxf(bm, __shfl_xor(bm,4));
    bm = fmaxf(bm, __shfl_xor(bm,8));
    bm = fmaxf(bm, __shfl_xor(bm,16));
    bm = fmaxf(bm, __shfl_xor(bm,32));
    float mn = fmaxf(m, bm);
    float r = __expf(m - mn);       // m=-inf -> 0
    float p = __expf(logit - mn);   // invalid lanes -> 0
    float ps = p;
    ps += __shfl_xor(ps,4); ps += __shfl_xor(ps,8); ps += __shfl_xor(ps,16); ps += __shfl_xor(ps,32);
    s = r*s + ps; m = mn;
    #pragma unroll
    for(int j=0;j<4;j++){
      uint4 w = vw[j];
      float4 a0 = acc[2*j], a1 = acc[2*j+1];
      a0.x = fmaf(a0.x, r, p*bflo(w.x)); a0.y = fmaf(a0.y, r, p*bfhi(w.x));
      a0.z = fmaf(a0.z, r, p*bflo(w.y)); a0.w = fmaf(a0.w, r, p*bfhi(w.y));
      a1.x = fmaf(a1.x, r, p*bflo(w.z)); a1.y = fmaf(a1.y, r, p*bfhi(w.z));
      a1.z = fmaf(a1.z, r, p*bflo(w.w)); a1.w = fmaf(a1.w, r, p*bfhi(w.w));
      acc[2*j] = a0; acc[2*j+1] = a1;
    }
  }
  #pragma unroll
  for(int j=0;j<8;j++){
    acc[j].x += __shfl_xor(acc[j].x,4);  acc[j].y += __shfl_xor(acc[j].y,4);
    acc[j].z += __shfl_xor(acc[j].z,4);  acc[j].w += __shfl_xor(acc[j].w,4);
    acc[j].x += __shfl_xor(acc[j].x,8);  acc[j].y += __shfl_xor(acc[j].y,8);
    acc[j].z += __shfl_xor(acc[j].z,8);  acc[j].w += __shfl_xor(acc[j].w,8);
    acc[j].x += __shfl_xor(acc[j].x,16); acc[j].y += __shfl_xor(acc[j].y,16);
    acc[j].z += __shfl_xor(acc[j].z,16); acc[j].w += __shfl_xor(acc[j].w,16);
    acc[j].x += __shfl_xor(acc[j].x,32); acc[j].y += __shfl_xor(acc[j].y,32);
    acc[j].z += __shfl_xor(acc[j].z,32); acc[j].w += __shfl_xor(acc[j].w,32);
  }
  float inv = (s > 0.f) ? (1.f/s) : 0.f;
  if(mode == 0){
    if(e_l == 0){
      const float* sk = (const float*)(QKVS + (size_t)node*ROW_BYTES + 1024) + h*32;
      float* op = out + (size_t)node*128 + h*32;
      #pragma unroll
      for(int j=0;j<8;j++){
        float4 sv = *(const float4*)(sk + j*4);
        float4 o;
        o.x = fmaxf(fmaf(acc[j].x, inv, sv.x), 0.f);
        o.y = fmaxf(fmaf(acc[j].y, inv, sv.y), 0.f);
        o.z = fmaxf(fmaf(acc[j].z, inv, sv.z), 0.f);
        o.w = fmaxf(fmaf(acc[j].w, inv, sv.w), 0.f);
        *(float4*)(op + j*4) = o;
      }
    }
  } else {
    float sc = inv*0.25f;
    #pragma unroll
    for(int j=0;j<8;j++){
      acc[j].x *= sc; acc[j].y *= sc; acc[j].z *= sc; acc[j].w *= sc;
      acc[j].x += __shfl_xor(acc[j].x,1); acc[j].y += __shfl_xor(acc[j].y,1);
      acc[j].z += __shfl_xor(acc[j].z,1); acc[j].w += __shfl_xor(acc[j].w,1);
      acc[j].x += __shfl_xor(acc[j].x,2); acc[j].y += __shfl_xor(acc[j].y,2);
      acc[j].z += __shfl_xor(acc[j].z,2); acc[j].w += __shfl_xor(acc[j].w,2);
    }
    if(lane == 0){
      const float* sk = (const float*)(QKVS + (size_t)node*ROW_BYTES + 1024);
      float* op = out + (size_t)node*32;
      #pragma unroll
      for(int j=0;j<8;j++){
        float4 sv = *(const float4*)(sk + j*4);
        float4 o = make_float4(acc[j].x+sv.x, acc[j].y+sv.y, acc[j].z+sv.z, acc[j].w+sv.w);
        *(float4*)(op + j*4) = o;
      }
    }
  }
}

extern "C" void kernel_launch(void* const* d_in, const int* in_sizes, int n_in,
                              void* d_out, int out_size, void* d_ws, size_t ws_size,
                              hipStream_t stream) {
  const float* x = (const float*)d_in[0];
  const int* ei = (const int*)d_in[1];
  int n = in_sizes[0]/DIN;
  int E = in_sizes[1]/2;
  const int* esrc = ei;
  const int* edst = ei + E;

  char* w = (char*)d_ws;
  auto alloc = [&](size_t bytes)->char*{
    char* p = w; w += (bytes + 255) & ~(size_t)255; return p;
  };
  int* offs = (int*)alloc((size_t)(n+1)*4);
  int* deg  = (int*)alloc((size_t)n*4);
  int* cur  = (int*)alloc((size_t)n*4);
  int* part = (int*)alloc(256*4);
  int* srcs = (int*)alloc((size_t)E*4);
  char* qkvs = alloc((size_t)n*ROW_BYTES);
  float* h1 = (float*)alloc((size_t)n*128*4);
  float* h2 = (float*)alloc((size_t)n*128*4);
  unsigned short* wt = (unsigned short*)alloc((size_t)12*16384*2);

  auto f = [&](int i)->const float*{ return (const float*)d_in[i]; };

  // weight prep (bf16, transposed)
  hipLaunchKernelGGL(k_wt, dim3(64,12), dim3(256), 0, stream,
                     f(2),f(4),f(6),f(8), f(10),f(12),f(14),f(16), f(18),f(20),f(22),f(24), wt);

  int SB = (n+255)/256;  // <=256 required for 2-level scan
  hipLaunchKernelGGL(k_zero, dim3((n+255)/256), dim3(256), 0, stream, deg, n);
  hipLaunchKernelGGL(k_zero, dim3((n+255)/256), dim3(256), 0, stream, cur, n);
  hipLaunchKernelGGL(k_count, dim3((E+255)/256), dim3(256), 0, stream, edst, deg, E);
  hipLaunchKernelGGL(k_scan1, dim3(SB), dim3(256), 0, stream, deg, offs, part, n);
  hipLaunchKernelGGL(k_scan2, dim3(1), dim3(256), 0, stream, part, SB);
  hipLaunchKernelGGL(k_scan3, dim3(SB), dim3(256), 0, stream, offs, part, n);
  hipLaunchKernelGGL(k_scatter, dim3((E+255)/256), dim3(256), 0, stream, esrc, edst, offs, cur, srcs, E);

  int RT = (n+63)/64;
  int AB = (n+3)/4;

  // layer 0
  hipLaunchKernelGGL(k_gemm, dim3(8, RT), dim3(256), 0, stream,
                     x, n, wt + 0*4*16384, f(3),f(5),f(7),f(9), 128, qkvs);
  hipLaunchKernelGGL(k_attn, dim3(AB), dim3(256), 0, stream, qkvs, offs, srcs, h1, 0, n);
  // layer 1
  hipLaunchKernelGGL(k_gemm, dim3(8, RT), dim3(256), 0, stream,
                     h1, n, wt + 1*4*16384, f(11),f(13),f(15),f(17), 128, qkvs);
  hipLaunchKernelGGL(k_attn, dim3(AB), dim3(256), 0, stream, qkvs, offs, srcs, h2, 0, n);
  // layer 2 (skip width 32, mean over heads)
  hipLaunchKernelGGL(k_gemm, dim3(8, RT), dim3(256), 0, stream,
                     h2, n, wt + 2*4*16384, f(19),f(21),f(23),f(25), 32, qkvs);
  hipLaunchKernelGGL(k_attn, dim3(AB), dim3(256), 0, stream, qkvs, offs, srcs, (float*)d_out, 1, n);
}

// Round 7
// 612.828 us; speedup vs baseline: 2.0881x; 1.0438x over previous
//
#include <hip/hip_runtime.h>
#include <cstdint>
#include <cstddef>

#define DIN 128        // feature width of all layer inputs (and Q/K/V width = H*DH)
#define ROW_BYTES 1536 // per-node row: Q fp32 [0,512) | KV bf16 interleaved [512,1024): head h -> K_h[32] @512+h*128, V_h[32] @512+h*128+64 | S fp32 [1024,1536)

typedef __attribute__((ext_vector_type(8))) short short8v;
typedef __attribute__((ext_vector_type(4))) float float4v;

// ---------------- CSR build ----------------
__global__ void k_zero(int* __restrict__ a, int n){
  int i = blockIdx.x*blockDim.x + threadIdx.x;
  if(i<n) a[i]=0;
}

__global__ void k_count(const int* __restrict__ dst, int* __restrict__ deg, int E){
  int i = blockIdx.x*blockDim.x + threadIdx.x;
  if(i<E) atomicAdd(&deg[dst[i]], 1);
}

__global__ void k_scan1(const int* __restrict__ deg, int* __restrict__ offs,
                        int* __restrict__ part, int n){
  __shared__ int sm[256];
  int t = threadIdx.x; int g = blockIdx.x*256 + t;
  int v = (g<n)? deg[g] : 0;
  sm[t] = v;
  for(int o=1;o<256;o<<=1){
    __syncthreads();
    int x = (t>=o)? sm[t-o] : 0;
    __syncthreads();
    sm[t] += x;
  }
  __syncthreads();
  if(g<n) offs[g+1] = sm[t];
  if(t==255) part[blockIdx.x] = sm[255];
}

__global__ void k_scan2(int* __restrict__ part, int nb){
  __shared__ int sm[256];
  int t=threadIdx.x;
  int v = (t<nb)? part[t] : 0;
  sm[t]=v;
  for(int o=1;o<256;o<<=1){ __syncthreads(); int x=(t>=o)?sm[t-o]:0; __syncthreads(); sm[t]+=x; }
  __syncthreads();
  if(t<nb) part[t] = sm[t]-v;  // exclusive prefix of block totals
}

__global__ void k_scan3(int* __restrict__ offs, const int* __restrict__ part, int n){
  int t=threadIdx.x; int g=blockIdx.x*256+t;
  if(g<n) offs[g+1] += part[blockIdx.x];
  if(g==0) offs[0]=0;
}

__global__ void k_scatter(const int* __restrict__ src, const int* __restrict__ dst,
                          const int* __restrict__ offs, int* __restrict__ cur,
                          int* __restrict__ srcs, int E){
  int i=blockIdx.x*blockDim.x+threadIdx.x;
  if(i<E){
    int d = dst[i];
    int p = atomicAdd(&cur[d],1);
    srcs[offs[d]+p] = src[i];
  }
}

// bf16 helpers (bf16 = top 16 bits of fp32; RNE pack)
__device__ inline unsigned f2bf(float x){
  unsigned u = __float_as_uint(x);
  return (u + 0x7FFFu + ((u>>16)&1u)) >> 16;
}
__device__ inline unsigned pack2(float a, float b){ return f2bf(a) | (f2bf(b)<<16); }
__device__ inline float bflo(unsigned w){ return __uint_as_float(w<<16); }
__device__ inline float bfhi(unsigned w){ return __uint_as_float(w & 0xFFFF0000u); }

// ---------------- weight prep: fp32 [din][dout] -> bf16 transposed [dout][din] ----------------
__global__ void k_wt(
  const float* __restrict__ W0, const float* __restrict__ W1, const float* __restrict__ W2,
  const float* __restrict__ W3, const float* __restrict__ W4, const float* __restrict__ W5,
  const float* __restrict__ W6, const float* __restrict__ W7, const float* __restrict__ W8,
  const float* __restrict__ W9, const float* __restrict__ W10, const float* __restrict__ W11,
  unsigned short* __restrict__ wt)
{
  int i = blockIdx.y;
  int e = blockIdx.x*256 + threadIdx.x;
  int dout = (i==11)? 32 : 128;
  if(e >= dout*128) return;
  const float* W;
  switch(i){
    case 0: W=W0; break; case 1: W=W1; break; case 2: W=W2; break; case 3: W=W3; break;
    case 4: W=W4; break; case 5: W=W5; break; case 6: W=W6; break; case 7: W=W7; break;
    case 8: W=W8; break; case 9: W=W9; break; case 10: W=W10; break; default: W=W11; break;
  }
  int c = e % dout, k = e / dout;
  wt[i*16384 + c*128 + k] = (unsigned short)f2bf(W[(size_t)k*dout + c]);
}

// ---------------- fused QKVS GEMM (bf16 MFMA, fp32 accum) ----------------
// grid: (8, row_tiles): blockIdx.x -> mat = bx>>1 (0..3), col-tile = bx&1.
// X: fp32 (xbf=0) or packed bf16 (xbf=1). Epilogue: Q,S fp32; K,V bf16 interleaved per head.
__global__ __launch_bounds__(256,4) void k_gemm(
  const void* __restrict__ Xv, int xbf, int nrows,
  const unsigned short* __restrict__ Wt,
  const float* __restrict__ bq, const float* __restrict__ bk,
  const float* __restrict__ bv, const float* __restrict__ bs,
  int ws_cols, char* __restrict__ out)
{
  __shared__ unsigned short Xs[64][136];
  __shared__ unsigned short Wsh[64][136];
  int t = threadIdx.x;
  int mat = blockIdx.x >> 1, ct = blockIdx.x & 1;
  int wcols = (mat==3)? ws_cols : 128;
  int col0 = ct*64;
  if(col0 >= wcols) return;
  const float* bias = (mat==0)?bq:(mat==1)?bk:(mat==2)?bv:bs;
  const unsigned short* Wm = Wt + mat*16384;
  int row0 = blockIdx.y*64;
  {
    int r = t>>2, kb = (t&3)*32;           // 64 rows x 4 thread-chunks of 32 k
    int gr = row0 + r;
    if(gr < nrows){
      if(xbf){
        const unsigned short* xp = (const unsigned short*)Xv + (size_t)gr*DIN + kb;
        #pragma unroll
        for(int j=0;j<4;j++)
          *(uint4*)&Xs[r][kb + j*8] = *(const uint4*)(xp + j*8);
      } else {
        const float* xp = (const float*)Xv + (size_t)gr*DIN + kb;
        #pragma unroll
        for(int j=0;j<4;j++){
          float4 fa = *(const float4*)(xp + j*8);
          float4 fb = *(const float4*)(xp + j*8 + 4);
          uint4 pk = make_uint4(pack2(fa.x,fa.y), pack2(fa.z,fa.w),
                                pack2(fb.x,fb.y), pack2(fb.z,fb.w));
          *(uint4*)&Xs[r][kb + j*8] = pk;
        }
      }
    } else {
      uint4 z = make_uint4(0,0,0,0);
      #pragma unroll
      for(int j=0;j<4;j++) *(uint4*)&Xs[r][kb + j*8] = z;
    }
    int c = r;
    int gc = col0 + c;
    if(gc < wcols){
      const unsigned short* wp = Wm + (size_t)gc*128 + kb;
      #pragma unroll
      for(int j=0;j<4;j++)
        *(uint4*)&Wsh[c][kb + j*8] = *(const uint4*)(wp + j*8);
    } else {
      uint4 z = make_uint4(0,0,0,0);
      #pragma unroll
      for(int j=0;j<4;j++) *(uint4*)&Wsh[c][kb + j*8] = z;
    }
  }
  __syncthreads();
  int wv = t>>6, l = t&63;
  int lr = l & 15, lk = (l>>4)*8;
  float4v acc[4];
  #pragma unroll
  for(int mt=0;mt<4;mt++) acc[mt] = (float4v){0.f,0.f,0.f,0.f};
  #pragma unroll
  for(int kk=0;kk<4;kk++){
    short8v b = *(const short8v*)&Wsh[wv*16 + lr][kk*32 + lk];
    #pragma unroll
    for(int mt=0;mt<4;mt++){
      short8v a = *(const short8v*)&Xs[mt*16 + lr][kk*32 + lk];
      acc[mt] = __builtin_amdgcn_mfma_f32_16x16x32_bf16(a, b, acc[mt], 0, 0, 0);
    }
  }
  int col = col0 + wv*16 + lr;
  bool cok = col < wcols;
  float bcol = cok ? bias[col] : 0.f;
  int rb = row0 + (l>>4)*4;
  #pragma unroll
  for(int mt=0;mt<4;mt++){
    #pragma unroll
    for(int j=0;j<4;j++){
      int r = rb + mt*16 + j;
      if(r < nrows && cok){
        float val = acc[mt][j] + bcol;
        char* rowp = out + (size_t)r*ROW_BYTES;
        if(mat==0)      *(float*)(rowp + col*4) = val;
        else if(mat==1) *(unsigned short*)(rowp + 512 + (col>>5)*128 + (col&31)*2) = (unsigned short)f2bf(val);
        else if(mat==2) *(unsigned short*)(rowp + 512 + (col>>5)*128 + 64 + (col&31)*2) = (unsigned short)f2bf(val);
        else            *(float*)(rowp + 1024 + col*4) = val;
      }
    }
  }
}

// ---------------- per-node attention (online softmax, CSR, bf16 KV interleaved) ----------------
// one wave per node; lane = e_l*4 + h. Gather per lane: contiguous 128B (K_h||V_h).
// End: reduce-scatter (30 shfl) -> lane owns channels (2*e_l, 2*e_l+1) of head h.
// mode 0: out bf16-packed [N][64] uints = relu(concat agg + skip)
// mode 1: out fp32 [N][32] = mean_h(agg) + skip
__global__ __launch_bounds__(256,4) void k_attn(
  const char* __restrict__ QKVS, const int* __restrict__ offs,
  const int* __restrict__ srcs, void* __restrict__ outv, int mode, int n)
{
  int wv = threadIdx.x>>6, lane = threadIdx.x&63;
  int node = blockIdx.x*4 + wv;
  if(node >= n) return;
  int h = lane & 3;
  int e_l = lane >> 2;
  const float rs = 0.17677669529663687f;  // 1/sqrt(32)
  const float* qp = (const float*)(QKVS + (size_t)node*ROW_BYTES) + h*32;
  float4 q[8];
  #pragma unroll
  for(int j=0;j<8;j++){
    float4 tq = *(const float4*)(qp + j*4);
    q[j] = make_float4(tq.x*rs, tq.y*rs, tq.z*rs, tq.w*rs);
  }
  int beg = offs[node], end = offs[node+1];
  float m = -__builtin_inff(), s = 0.f;
  float4 acc[8];
  #pragma unroll
  for(int j=0;j<8;j++) acc[j] = make_float4(0.f,0.f,0.f,0.f);

  for(int b0 = beg; b0 < end; b0 += 16){
    int idx = b0 + e_l;
    bool valid = idx < end;
    int sj = srcs[valid ? idx : beg];
    const char* base = QKVS + (size_t)sj*ROW_BYTES + 512 + h*128;  // K_h @0, V_h @64
    // V chunk first, pinned live across dot+softmax
    uint4 vw[4];
    const uint4* vp = (const uint4*)(base + 64);
    #pragma unroll
    for(int j=0;j<4;j++) vw[j] = vp[j];
    #pragma unroll
    for(int j=0;j<4;j++)
      asm volatile("" : "+v"(vw[j].x), "+v"(vw[j].y), "+v"(vw[j].z), "+v"(vw[j].w));
    const uint4* kp = (const uint4*)base;
    float dot = 0.f;
    #pragma unroll
    for(int j=0;j<4;j++){
      uint4 kw = kp[j];
      float4 qa = q[2*j], qb = q[2*j+1];
      dot += qa.x*bflo(kw.x) + qa.y*bfhi(kw.x) + qa.z*bflo(kw.y) + qa.w*bfhi(kw.y);
      dot += qb.x*bflo(kw.z) + qb.y*bfhi(kw.z) + qb.z*bflo(kw.w) + qb.w*bfhi(kw.w);
    }
    float logit = valid ? dot : -__builtin_inff();
    float bm = logit;
    bm = fmaxf(bm, __shfl_xor(bm,4));
    bm = fmaxf(bm, __shfl_xor(bm,8));
    bm = fmaxf(bm, __shfl_xor(bm,16));
    bm = fmaxf(bm, __shfl_xor(bm,32));
    float mn = fmaxf(m, bm);
    float r = __expf(m - mn);       // m=-inf -> 0
    float p = __expf(logit - mn);   // invalid lanes -> 0
    float ps = p;
    ps += __shfl_xor(ps,4); ps += __shfl_xor(ps,8); ps += __shfl_xor(ps,16); ps += __shfl_xor(ps,32);
    s = r*s + ps; m = mn;
    #pragma unroll
    for(int j=0;j<4;j++){
      uint4 w = vw[j];
      float4 a0 = acc[2*j], a1 = acc[2*j+1];
      a0.x = fmaf(a0.x, r, p*bflo(w.x)); a0.y = fmaf(a0.y, r, p*bfhi(w.x));
      a0.z = fmaf(a0.z, r, p*bflo(w.y)); a0.w = fmaf(a0.w, r, p*bfhi(w.y));
      a1.x = fmaf(a1.x, r, p*bflo(w.z)); a1.y = fmaf(a1.y, r, p*bfhi(w.z));
      a1.z = fmaf(a1.z, r, p*bflo(w.w)); a1.w = fmaf(a1.w, r, p*bfhi(w.w));
      acc[2*j] = a0; acc[2*j+1] = a1;
    }
  }
  // ---- reduce-scatter over edge lanes: 30 shfl total ----
  int b5 = (lane>>5)&1, b4 = (lane>>4)&1, b3 = (lane>>3)&1, b2 = (lane>>2)&1;
  float4 r4[4];
  #pragma unroll
  for(int j=0;j<4;j++){
    float4 keep = b5 ? acc[j+4] : acc[j];
    float4 send = b5 ? acc[j]   : acc[j+4];
    keep.x += __shfl_xor(send.x,32); keep.y += __shfl_xor(send.y,32);
    keep.z += __shfl_xor(send.z,32); keep.w += __shfl_xor(send.w,32);
    r4[j] = keep;   // ch = 16*b5 + 4*j + c
  }
  float4 r2[2];
  #pragma unroll
  for(int j=0;j<2;j++){
    float4 keep = b4 ? r4[j+2] : r4[j];
    float4 send = b4 ? r4[j]   : r4[j+2];
    keep.x += __shfl_xor(send.x,16); keep.y += __shfl_xor(send.y,16);
    keep.z += __shfl_xor(send.z,16); keep.w += __shfl_xor(send.w,16);
    r2[j] = keep;   // ch = 16*b5 + 8*b4 + 4*j + c
  }
  float4 r1;
  {
    float4 keep = b3 ? r2[1] : r2[0];
    float4 send = b3 ? r2[0] : r2[1];
    keep.x += __shfl_xor(send.x,8); keep.y += __shfl_xor(send.y,8);
    keep.z += __shfl_xor(send.z,8); keep.w += __shfl_xor(send.w,8);
    r1 = keep;      // ch = 16*b5 + 8*b4 + 4*b3 + c
  }
  float fx, fy;
  {
    float kx = b2 ? r1.z : r1.x, ky = b2 ? r1.w : r1.y;
    float sx = b2 ? r1.x : r1.z, sy = b2 ? r1.y : r1.w;
    fx = kx + __shfl_xor(sx,4);
    fy = ky + __shfl_xor(sy,4);   // ch pair = (2*e_l, 2*e_l+1) of head h
  }
  float inv = (s > 0.f) ? (1.f/s) : 0.f;   // per-head (s reduced over e-lanes only)
  if(mode == 0){
    const float* sk = (const float*)(QKVS + (size_t)node*ROW_BYTES + 1024);
    float2 sv = *(const float2*)(sk + h*32 + 2*e_l);
    float ox = fmaxf(fmaf(fx, inv, sv.x), 0.f);
    float oy = fmaxf(fmaf(fy, inv, sv.y), 0.f);
    ((unsigned*)outv)[(size_t)node*64 + h*16 + e_l] = pack2(ox, oy);
  } else {
    float sc = inv*0.25f;
    float ox = fx*sc, oy = fy*sc;
    ox += __shfl_xor(ox,1); oy += __shfl_xor(oy,1);
    ox += __shfl_xor(ox,2); oy += __shfl_xor(oy,2);
    if(h == 0){
      const float* sk = (const float*)(QKVS + (size_t)node*ROW_BYTES + 1024);
      float2 sv = *(const float2*)(sk + 2*e_l);
      float* op = (float*)outv + (size_t)node*32 + 2*e_l;
      op[0] = ox + sv.x; op[1] = oy + sv.y;
    }
  }
}

extern "C" void kernel_launch(void* const* d_in, const int* in_sizes, int n_in,
                              void* d_out, int out_size, void* d_ws, size_t ws_size,
                              hipStream_t stream) {
  const float* x = (const float*)d_in[0];
  const int* ei = (const int*)d_in[1];
  int n = in_sizes[0]/DIN;
  int E = in_sizes[1]/2;
  const int* esrc = ei;
  const int* edst = ei + E;

  char* w = (char*)d_ws;
  auto alloc = [&](size_t bytes)->char*{
    char* p = w; w += (bytes + 255) & ~(size_t)255; return p;
  };
  int* offs = (int*)alloc((size_t)(n+1)*4);
  int* deg  = (int*)alloc((size_t)n*4);
  int* cur  = (int*)alloc((size_t)n*4);
  int* part = (int*)alloc(256*4);
  int* srcs = (int*)alloc((size_t)E*4);
  char* qkvs = alloc((size_t)n*ROW_BYTES);
  unsigned short* h1 = (unsigned short*)alloc((size_t)n*128*2);
  unsigned short* h2 = (unsigned short*)alloc((size_t)n*128*2);
  unsigned short* wt = (unsigned short*)alloc((size_t)12*16384*2);

  auto f = [&](int i)->const float*{ return (const float*)d_in[i]; };

  // weight prep (bf16, transposed)
  hipLaunchKernelGGL(k_wt, dim3(64,12), dim3(256), 0, stream,
                     f(2),f(4),f(6),f(8), f(10),f(12),f(14),f(16), f(18),f(20),f(22),f(24), wt);

  int SB = (n+255)/256;  // <=256 required for 2-level scan
  hipLaunchKernelGGL(k_zero, dim3((n+255)/256), dim3(256), 0, stream, deg, n);
  hipLaunchKernelGGL(k_zero, dim3((n+255)/256), dim3(256), 0, stream, cur, n);
  hipLaunchKernelGGL(k_count, dim3((E+255)/256), dim3(256), 0, stream, edst, deg, E);
  hipLaunchKernelGGL(k_scan1, dim3(SB), dim3(256), 0, stream, deg, offs, part, n);
  hipLaunchKernelGGL(k_scan2, dim3(1), dim3(256), 0, stream, part, SB);
  hipLaunchKernelGGL(k_scan3, dim3(SB), dim3(256), 0, stream, offs, part, n);
  hipLaunchKernelGGL(k_scatter, dim3((E+255)/256), dim3(256), 0, stream, esrc, edst, offs, cur, srcs, E);

  int RT = (n+63)/64;
  int AB = (n+3)/4;

  // layer 0
  hipLaunchKernelGGL(k_gemm, dim3(8, RT), dim3(256), 0, stream,
                     (const void*)x, 0, n, wt + 0*4*16384, f(3),f(5),f(7),f(9), 128, qkvs);
  hipLaunchKernelGGL(k_attn, dim3(AB), dim3(256), 0, stream, qkvs, offs, srcs, (void*)h1, 0, n);
  // layer 1
  hipLaunchKernelGGL(k_gemm, dim3(8, RT), dim3(256), 0, stream,
                     (const void*)h1, 1, n, wt + 1*4*16384, f(11),f(13),f(15),f(17), 128, qkvs);
  hipLaunchKernelGGL(k_attn, dim3(AB), dim3(256), 0, stream, qkvs, offs, srcs, (void*)h2, 0, n);
  // layer 2 (skip width 32, mean over heads)
  hipLaunchKernelGGL(k_gemm, dim3(8, RT), dim3(256), 0, stream,
                     (const void*)h2, 1, n, wt + 2*4*16384, f(19),f(21),f(23),f(25), 32, qkvs);
  hipLaunchKernelGGL(k_attn, dim3(AB), dim3(256), 0, stream, qkvs, offs, srcs, d_out, 1, n);
}

// Round 8
// 576.106 us; speedup vs baseline: 2.2212x; 1.0637x over previous
//
#include <hip/hip_runtime.h>
#include <cstdint>
#include <cstddef>

#define DIN 128        // feature width of all layer inputs (and Q/K/V width = H*DH)
#define ROW_BYTES 1536 // per-node row: Q fp32 [0,512) | KV bf16 chunk-transposed [512,1024):
                       //   K: chunk j (0..3) at 512+j*64, holds [h0|h1|h2|h3] x 16B (8 bf16 each)
                       //   V: chunk j at 768+j*64, same head-interleave | S fp32 [1024,1536)

typedef __attribute__((ext_vector_type(8))) short short8v;
typedef __attribute__((ext_vector_type(4))) float float4v;

// ---------------- CSR build ----------------
__global__ void k_zero(int* __restrict__ a, int n){
  int i = blockIdx.x*blockDim.x + threadIdx.x;
  if(i<n) a[i]=0;
}

__global__ void k_count(const int* __restrict__ dst, int* __restrict__ deg, int E){
  int i = blockIdx.x*blockDim.x + threadIdx.x;
  if(i<E) atomicAdd(&deg[dst[i]], 1);
}

__global__ void k_scan1(const int* __restrict__ deg, int* __restrict__ offs,
                        int* __restrict__ part, int n){
  __shared__ int sm[256];
  int t = threadIdx.x; int g = blockIdx.x*256 + t;
  int v = (g<n)? deg[g] : 0;
  sm[t] = v;
  for(int o=1;o<256;o<<=1){
    __syncthreads();
    int x = (t>=o)? sm[t-o] : 0;
    __syncthreads();
    sm[t] += x;
  }
  __syncthreads();
  if(g<n) offs[g+1] = sm[t];
  if(t==255) part[blockIdx.x] = sm[255];
}

__global__ void k_scan2(int* __restrict__ part, int nb){
  __shared__ int sm[256];
  int t=threadIdx.x;
  int v = (t<nb)? part[t] : 0;
  sm[t]=v;
  for(int o=1;o<256;o<<=1){ __syncthreads(); int x=(t>=o)?sm[t-o]:0; __syncthreads(); sm[t]+=x; }
  __syncthreads();
  if(t<nb) part[t] = sm[t]-v;  // exclusive prefix of block totals
}

__global__ void k_scan3(int* __restrict__ offs, const int* __restrict__ part, int n){
  int t=threadIdx.x; int g=blockIdx.x*256+t;
  if(g<n) offs[g+1] += part[blockIdx.x];
  if(g==0) offs[0]=0;
}

__global__ void k_scatter(const int* __restrict__ src, const int* __restrict__ dst,
                          const int* __restrict__ offs, int* __restrict__ cur,
                          int* __restrict__ srcs, int E){
  int i=blockIdx.x*blockDim.x+threadIdx.x;
  if(i<E){
    int d = dst[i];
    int p = atomicAdd(&cur[d],1);
    srcs[offs[d]+p] = src[i];
  }
}

// bf16 helpers (bf16 = top 16 bits of fp32; RNE pack)
__device__ inline unsigned f2bf(float x){
  unsigned u = __float_as_uint(x);
  return (u + 0x7FFFu + ((u>>16)&1u)) >> 16;
}
__device__ inline unsigned pack2(float a, float b){ return f2bf(a) | (f2bf(b)<<16); }
__device__ inline float bflo(unsigned w){ return __uint_as_float(w<<16); }
__device__ inline float bfhi(unsigned w){ return __uint_as_float(w & 0xFFFF0000u); }

// ---------------- weight prep: fp32 [din][dout] -> bf16 transposed [dout][din] ----------------
__global__ void k_wt(
  const float* __restrict__ W0, const float* __restrict__ W1, const float* __restrict__ W2,
  const float* __restrict__ W3, const float* __restrict__ W4, const float* __restrict__ W5,
  const float* __restrict__ W6, const float* __restrict__ W7, const float* __restrict__ W8,
  const float* __restrict__ W9, const float* __restrict__ W10, const float* __restrict__ W11,
  unsigned short* __restrict__ wt)
{
  int i = blockIdx.y;
  int e = blockIdx.x*256 + threadIdx.x;
  int dout = (i==11)? 32 : 128;
  if(e >= dout*128) return;
  const float* W;
  switch(i){
    case 0: W=W0; break; case 1: W=W1; break; case 2: W=W2; break; case 3: W=W3; break;
    case 4: W=W4; break; case 5: W=W5; break; case 6: W=W6; break; case 7: W=W7; break;
    case 8: W=W8; break; case 9: W=W9; break; case 10: W=W10; break; default: W=W11; break;
  }
  int c = e % dout, k = e / dout;
  wt[i*16384 + c*128 + k] = (unsigned short)f2bf(W[(size_t)k*dout + c]);
}

// ---------------- fused QKVS GEMM (bf16 MFMA, fp32 accum) ----------------
// grid: (8, row_tiles): blockIdx.x -> mat = bx>>1 (0..3), col-tile = bx&1.
// X: fp32 (xbf=0) or packed bf16 (xbf=1).
// Epilogue: Q,S fp32; K,V bf16 chunk-transposed (see ROW_BYTES comment).
__global__ __launch_bounds__(256,4) void k_gemm(
  const void* __restrict__ Xv, int xbf, int nrows,
  const unsigned short* __restrict__ Wt,
  const float* __restrict__ bq, const float* __restrict__ bk,
  const float* __restrict__ bv, const float* __restrict__ bs,
  int ws_cols, char* __restrict__ out)
{
  __shared__ unsigned short Xs[64][136];
  __shared__ unsigned short Wsh[64][136];
  int t = threadIdx.x;
  int mat = blockIdx.x >> 1, ct = blockIdx.x & 1;
  int wcols = (mat==3)? ws_cols : 128;
  int col0 = ct*64;
  if(col0 >= wcols) return;
  const float* bias = (mat==0)?bq:(mat==1)?bk:(mat==2)?bv:bs;
  const unsigned short* Wm = Wt + mat*16384;
  int row0 = blockIdx.y*64;
  {
    int r = t>>2, kb = (t&3)*32;           // 64 rows x 4 thread-chunks of 32 k
    int gr = row0 + r;
    if(gr < nrows){
      if(xbf){
        const unsigned short* xp = (const unsigned short*)Xv + (size_t)gr*DIN + kb;
        #pragma unroll
        for(int j=0;j<4;j++)
          *(uint4*)&Xs[r][kb + j*8] = *(const uint4*)(xp + j*8);
      } else {
        const float* xp = (const float*)Xv + (size_t)gr*DIN + kb;
        #pragma unroll
        for(int j=0;j<4;j++){
          float4 fa = *(const float4*)(xp + j*8);
          float4 fb = *(const float4*)(xp + j*8 + 4);
          uint4 pk = make_uint4(pack2(fa.x,fa.y), pack2(fa.z,fa.w),
                                pack2(fb.x,fb.y), pack2(fb.z,fb.w));
          *(uint4*)&Xs[r][kb + j*8] = pk;
        }
      }
    } else {
      uint4 z = make_uint4(0,0,0,0);
      #pragma unroll
      for(int j=0;j<4;j++) *(uint4*)&Xs[r][kb + j*8] = z;
    }
    int c = r;
    int gc = col0 + c;
    if(gc < wcols){
      const unsigned short* wp = Wm + (size_t)gc*128 + kb;
      #pragma unroll
      for(int j=0;j<4;j++)
        *(uint4*)&Wsh[c][kb + j*8] = *(const uint4*)(wp + j*8);
    } else {
      uint4 z = make_uint4(0,0,0,0);
      #pragma unroll
      for(int j=0;j<4;j++) *(uint4*)&Wsh[c][kb + j*8] = z;
    }
  }
  __syncthreads();
  int wv = t>>6, l = t&63;
  int lr = l & 15, lk = (l>>4)*8;
  float4v acc[4];
  #pragma unroll
  for(int mt=0;mt<4;mt++) acc[mt] = (float4v){0.f,0.f,0.f,0.f};
  #pragma unroll
  for(int kk=0;kk<4;kk++){
    short8v b = *(const short8v*)&Wsh[wv*16 + lr][kk*32 + lk];
    #pragma unroll
    for(int mt=0;mt<4;mt++){
      short8v a = *(const short8v*)&Xs[mt*16 + lr][kk*32 + lk];
      acc[mt] = __builtin_amdgcn_mfma_f32_16x16x32_bf16(a, b, acc[mt], 0, 0, 0);
    }
  }
  int col = col0 + wv*16 + lr;
  bool cok = col < wcols;
  float bcol = cok ? bias[col] : 0.f;
  int rb = row0 + (l>>4)*4;
  #pragma unroll
  for(int mt=0;mt<4;mt++){
    #pragma unroll
    for(int j=0;j<4;j++){
      int r = rb + mt*16 + j;
      if(r < nrows && cok){
        float val = acc[mt][j] + bcol;
        char* rowp = out + (size_t)r*ROW_BYTES;
        if(mat==0)      *(float*)(rowp + col*4) = val;
        else if(mat==3) *(float*)(rowp + 1024 + col*4) = val;
        else {
          // chunk-transposed KV: head h = col>>5, elem d = col&31
          int h = col>>5, d = col&31;
          int off = ((mat==1)?512:768) + (d>>3)*64 + h*16 + (d&7)*2;
          *(unsigned short*)(rowp + off) = (unsigned short)f2bf(val);
        }
      }
    }
  }
}

// ---------------- per-node attention (online softmax, CSR, chunk-transposed bf16 KV) ----------------
// one wave per node; lane = e_l*4 + h. Gather: the 4 head-lanes of an edge read
// ONE contiguous 64B sector per instruction (chunk j: [h0|h1|h2|h3]x16B).
// End: reduce-scatter (30 shfl) -> lane owns channels (2*e_l, 2*e_l+1) of head h.
// mode 0: out bf16-packed [N][64] uints = relu(concat agg + skip)
// mode 1: out fp32 [N][32] = mean_h(agg) + skip
__global__ __launch_bounds__(256,4) void k_attn(
  const char* __restrict__ QKVS, const int* __restrict__ offs,
  const int* __restrict__ srcs, void* __restrict__ outv, int mode, int n)
{
  int wv = threadIdx.x>>6, lane = threadIdx.x&63;
  int node = blockIdx.x*4 + wv;
  if(node >= n) return;
  int h = lane & 3;
  int e_l = lane >> 2;
  const float rs = 0.17677669529663687f;  // 1/sqrt(32)
  const float* qp = (const float*)(QKVS + (size_t)node*ROW_BYTES) + h*32;
  float4 q[8];
  #pragma unroll
  for(int j=0;j<8;j++){
    float4 tq = *(const float4*)(qp + j*4);
    q[j] = make_float4(tq.x*rs, tq.y*rs, tq.z*rs, tq.w*rs);
  }
  int beg = offs[node], end = offs[node+1];
  float m = -__builtin_inff(), s = 0.f;
  float4 acc[8];
  #pragma unroll
  for(int j=0;j<8;j++) acc[j] = make_float4(0.f,0.f,0.f,0.f);

  for(int b0 = beg; b0 < end; b0 += 16){
    int idx = b0 + e_l;
    bool valid = idx < end;
    int sj = srcs[valid ? idx : beg];
    const char* base = QKVS + (size_t)sj*ROW_BYTES + 512 + h*16;  // chunk-transposed
    // V chunks first, pinned live across dot+softmax
    uint4 vw[4];
    #pragma unroll
    for(int j=0;j<4;j++) vw[j] = *(const uint4*)(base + 256 + j*64);
    #pragma unroll
    for(int j=0;j<4;j++)
      asm volatile("" : "+v"(vw[j].x), "+v"(vw[j].y), "+v"(vw[j].z), "+v"(vw[j].w));
    float dot = 0.f;
    #pragma unroll
    for(int j=0;j<4;j++){
      uint4 kw = *(const uint4*)(base + j*64);
      float4 qa = q[2*j], qb = q[2*j+1];
      dot += qa.x*bflo(kw.x) + qa.y*bfhi(kw.x) + qa.z*bflo(kw.y) + qa.w*bfhi(kw.y);
      dot += qb.x*bflo(kw.z) + qb.y*bfhi(kw.z) + qb.z*bflo(kw.w) + qb.w*bfhi(kw.w);
    }
    float logit = valid ? dot : -__builtin_inff();
    float bm = logit;
    bm = fmaxf(bm, __shfl_xor(bm,4));
    bm = fmaxf(bm, __shfl_xor(bm,8));
    bm = fmaxf(bm, __shfl_xor(bm,16));
    bm = fmaxf(bm, __shfl_xor(bm,32));
    float mn = fmaxf(m, bm);
    float r = __expf(m - mn);       // m=-inf -> 0
    float p = __expf(logit - mn);   // invalid lanes -> 0
    float ps = p;
    ps += __shfl_xor(ps,4); ps += __shfl_xor(ps,8); ps += __shfl_xor(ps,16); ps += __shfl_xor(ps,32);
    s = r*s + ps; m = mn;
    #pragma unroll
    for(int j=0;j<4;j++){
      uint4 w = vw[j];
      float4 a0 = acc[2*j], a1 = acc[2*j+1];
      a0.x = fmaf(a0.x, r, p*bflo(w.x)); a0.y = fmaf(a0.y, r, p*bfhi(w.x));
      a0.z = fmaf(a0.z, r, p*bflo(w.y)); a0.w = fmaf(a0.w, r, p*bfhi(w.y));
      a1.x = fmaf(a1.x, r, p*bflo(w.z)); a1.y = fmaf(a1.y, r, p*bfhi(w.z));
      a1.z = fmaf(a1.z, r, p*bflo(w.w)); a1.w = fmaf(a1.w, r, p*bfhi(w.w));
      acc[2*j] = a0; acc[2*j+1] = a1;
    }
  }
  // ---- reduce-scatter over edge lanes: 30 shfl total ----
  int b5 = (lane>>5)&1, b4 = (lane>>4)&1, b3 = (lane>>3)&1, b2 = (lane>>2)&1;
  float4 r4[4];
  #pragma unroll
  for(int j=0;j<4;j++){
    float4 keep = b5 ? acc[j+4] : acc[j];
    float4 send = b5 ? acc[j]   : acc[j+4];
    keep.x += __shfl_xor(send.x,32); keep.y += __shfl_xor(send.y,32);
    keep.z += __shfl_xor(send.z,32); keep.w += __shfl_xor(send.w,32);
    r4[j] = keep;   // ch = 16*b5 + 4*j + c
  }
  float4 r2[2];
  #pragma unroll
  for(int j=0;j<2;j++){
    float4 keep = b4 ? r4[j+2] : r4[j];
    float4 send = b4 ? r4[j]   : r4[j+2];
    keep.x += __shfl_xor(send.x,16); keep.y += __shfl_xor(send.y,16);
    keep.z += __shfl_xor(send.z,16); keep.w += __shfl_xor(send.w,16);
    r2[j] = keep;   // ch = 16*b5 + 8*b4 + 4*j + c
  }
  float4 r1;
  {
    float4 keep = b3 ? r2[1] : r2[0];
    float4 send = b3 ? r2[0] : r2[1];
    keep.x += __shfl_xor(send.x,8); keep.y += __shfl_xor(send.y,8);
    keep.z += __shfl_xor(send.z,8); keep.w += __shfl_xor(send.w,8);
    r1 = keep;      // ch = 16*b5 + 8*b4 + 4*b3 + c
  }
  float fx, fy;
  {
    float kx = b2 ? r1.z : r1.x, ky = b2 ? r1.w : r1.y;
    float sx = b2 ? r1.x : r1.z, sy = b2 ? r1.y : r1.w;
    fx = kx + __shfl_xor(sx,4);
    fy = ky + __shfl_xor(sy,4);   // ch pair = (2*e_l, 2*e_l+1) of head h
  }
  float inv = (s > 0.f) ? (1.f/s) : 0.f;   // per-head (s reduced over e-lanes only)
  if(mode == 0){
    const float* sk = (const float*)(QKVS + (size_t)node*ROW_BYTES + 1024);
    float2 sv = *(const float2*)(sk + h*32 + 2*e_l);
    float ox = fmaxf(fmaf(fx, inv, sv.x), 0.f);
    float oy = fmaxf(fmaf(fy, inv, sv.y), 0.f);
    ((unsigned*)outv)[(size_t)node*64 + h*16 + e_l] = pack2(ox, oy);
  } else {
    float sc = inv*0.25f;
    float ox = fx*sc, oy = fy*sc;
    ox += __shfl_xor(ox,1); oy += __shfl_xor(oy,1);
    ox += __shfl_xor(ox,2); oy += __shfl_xor(oy,2);
    if(h == 0){
      const float* sk = (const float*)(QKVS + (size_t)node*ROW_BYTES + 1024);
      float2 sv = *(const float2*)(sk + 2*e_l);
      float* op = (float*)outv + (size_t)node*32 + 2*e_l;
      op[0] = ox + sv.x; op[1] = oy + sv.y;
    }
  }
}

extern "C" void kernel_launch(void* const* d_in, const int* in_sizes, int n_in,
                              void* d_out, int out_size, void* d_ws, size_t ws_size,
                              hipStream_t stream) {
  const float* x = (const float*)d_in[0];
  const int* ei = (const int*)d_in[1];
  int n = in_sizes[0]/DIN;
  int E = in_sizes[1]/2;
  const int* esrc = ei;
  const int* edst = ei + E;

  char* w = (char*)d_ws;
  auto alloc = [&](size_t bytes)->char*{
    char* p = w; w += (bytes + 255) & ~(size_t)255; return p;
  };
  int* offs = (int*)alloc((size_t)(n+1)*4);
  int* deg  = (int*)alloc((size_t)n*4);
  int* cur  = (int*)alloc((size_t)n*4);
  int* part = (int*)alloc(256*4);
  int* srcs = (int*)alloc((size_t)E*4);
  char* qkvs = alloc((size_t)n*ROW_BYTES);
  unsigned short* h1 = (unsigned short*)alloc((size_t)n*128*2);
  unsigned short* h2 = (unsigned short*)alloc((size_t)n*128*2);
  unsigned short* wt = (unsigned short*)alloc((size_t)12*16384*2);

  auto f = [&](int i)->const float*{ return (const float*)d_in[i]; };

  // weight prep (bf16, transposed)
  hipLaunchKernelGGL(k_wt, dim3(64,12), dim3(256), 0, stream,
                     f(2),f(4),f(6),f(8), f(10),f(12),f(14),f(16), f(18),f(20),f(22),f(24), wt);

  int SB = (n+255)/256;  // <=256 required for 2-level scan
  hipLaunchKernelGGL(k_zero, dim3((n+255)/256), dim3(256), 0, stream, deg, n);
  hipLaunchKernelGGL(k_zero, dim3((n+255)/256), dim3(256), 0, stream, cur, n);
  hipLaunchKernelGGL(k_count, dim3((E+255)/256), dim3(256), 0, stream, edst, deg, E);
  hipLaunchKernelGGL(k_scan1, dim3(SB), dim3(256), 0, stream, deg, offs, part, n);
  hipLaunchKernelGGL(k_scan2, dim3(1), dim3(256), 0, stream, part, SB);
  hipLaunchKernelGGL(k_scan3, dim3(SB), dim3(256), 0, stream, offs, part, n);
  hipLaunchKernelGGL(k_scatter, dim3((E+255)/256), dim3(256), 0, stream, esrc, edst, offs, cur, srcs, E);

  int RT = (n+63)/64;
  int AB = (n+3)/4;

  // layer 0
  hipLaunchKernelGGL(k_gemm, dim3(8, RT), dim3(256), 0, stream,
                     (const void*)x, 0, n, wt + 0*4*16384, f(3),f(5),f(7),f(9), 128, qkvs);
  hipLaunchKernelGGL(k_attn, dim3(AB), dim3(256), 0, stream, qkvs, offs, srcs, (void*)h1, 0, n);
  // layer 1
  hipLaunchKernelGGL(k_gemm, dim3(8, RT), dim3(256), 0, stream,
                     (const void*)h1, 1, n, wt + 1*4*16384, f(11),f(13),f(15),f(17), 128, qkvs);
  hipLaunchKernelGGL(k_attn, dim3(AB), dim3(256), 0, stream, qkvs, offs, srcs, (void*)h2, 0, n);
  // layer 2 (skip width 32, mean over heads)
  hipLaunchKernelGGL(k_gemm, dim3(8, RT), dim3(256), 0, stream,
                     (const void*)h2, 1, n, wt + 2*4*16384, f(19),f(21),f(23),f(25), 32, qkvs);
  hipLaunchKernelGGL(k_attn, dim3(AB), dim3(256), 0, stream, qkvs, offs, srcs, d_out, 1, n);
}

// Round 9
// 464.566 us; speedup vs baseline: 2.7545x; 1.2401x over previous
//
#include <hip/hip_runtime.h>
#include <cstdint>
#include <cstddef>

#define DIN 128        // feature width of all layer inputs (and Q/K/V width = H*DH)
#define ROW_BYTES 1280 // per-node row: Q bf16 [0,256) (head h at h*64, 32 bf16 linear)
                       //   K bf16 chunk-transposed [256,512): chunk j at 256+j*64 = [h0|h1|h2|h3]x16B
                       //   V bf16 chunk-transposed [512,768): chunk j at 512+j*64
                       //   S fp32 [768,1280)

typedef __attribute__((ext_vector_type(8))) short short8v;
typedef __attribute__((ext_vector_type(4))) float float4v;

// ---------------- CSR build ----------------
__global__ void k_zero(int* __restrict__ a, int n){
  int i = blockIdx.x*blockDim.x + threadIdx.x;
  if(i<n) a[i]=0;
}

__global__ void k_count(const int* __restrict__ dst, int* __restrict__ deg, int E){
  int i = blockIdx.x*blockDim.x + threadIdx.x;
  if(i<E) atomicAdd(&deg[dst[i]], 1);
}

__global__ void k_scan1(const int* __restrict__ deg, int* __restrict__ offs,
                        int* __restrict__ part, int n){
  __shared__ int sm[256];
  int t = threadIdx.x; int g = blockIdx.x*256 + t;
  int v = (g<n)? deg[g] : 0;
  sm[t] = v;
  for(int o=1;o<256;o<<=1){
    __syncthreads();
    int x = (t>=o)? sm[t-o] : 0;
    __syncthreads();
    sm[t] += x;
  }
  __syncthreads();
  if(g<n) offs[g+1] = sm[t];
  if(t==255) part[blockIdx.x] = sm[255];
}

__global__ void k_scan2(int* __restrict__ part, int nb){
  __shared__ int sm[256];
  int t=threadIdx.x;
  int v = (t<nb)? part[t] : 0;
  sm[t]=v;
  for(int o=1;o<256;o<<=1){ __syncthreads(); int x=(t>=o)?sm[t-o]:0; __syncthreads(); sm[t]+=x; }
  __syncthreads();
  if(t<nb) part[t] = sm[t]-v;  // exclusive prefix of block totals
}

__global__ void k_scan3(int* __restrict__ offs, const int* __restrict__ part, int n){
  int t=threadIdx.x; int g=blockIdx.x*256+t;
  if(g<n) offs[g+1] += part[blockIdx.x];
  if(g==0) offs[0]=0;
}

__global__ void k_scatter(const int* __restrict__ src, const int* __restrict__ dst,
                          const int* __restrict__ offs, int* __restrict__ cur,
                          int* __restrict__ srcs, int E){
  int i=blockIdx.x*blockDim.x+threadIdx.x;
  if(i<E){
    int d = dst[i];
    int p = atomicAdd(&cur[d],1);
    srcs[offs[d]+p] = src[i];
  }
}

// bf16 helpers (bf16 = top 16 bits of fp32; RNE pack)
__device__ inline unsigned f2bf(float x){
  unsigned u = __float_as_uint(x);
  return (u + 0x7FFFu + ((u>>16)&1u)) >> 16;
}
__device__ inline unsigned pack2(float a, float b){ return f2bf(a) | (f2bf(b)<<16); }
__device__ inline float bflo(unsigned w){ return __uint_as_float(w<<16); }
__device__ inline float bfhi(unsigned w){ return __uint_as_float(w & 0xFFFF0000u); }

// ---------------- weight prep: fp32 [din][dout] -> bf16 transposed [dout][din] ----------------
__global__ void k_wt(
  const float* __restrict__ W0, const float* __restrict__ W1, const float* __restrict__ W2,
  const float* __restrict__ W3, const float* __restrict__ W4, const float* __restrict__ W5,
  const float* __restrict__ W6, const float* __restrict__ W7, const float* __restrict__ W8,
  const float* __restrict__ W9, const float* __restrict__ W10, const float* __restrict__ W11,
  unsigned short* __restrict__ wt)
{
  int i = blockIdx.y;
  int e = blockIdx.x*256 + threadIdx.x;
  int dout = (i==11)? 32 : 128;
  if(e >= dout*128) return;
  const float* W;
  switch(i){
    case 0: W=W0; break; case 1: W=W1; break; case 2: W=W2; break; case 3: W=W3; break;
    case 4: W=W4; break; case 5: W=W5; break; case 6: W=W6; break; case 7: W=W7; break;
    case 8: W=W8; break; case 9: W=W9; break; case 10: W=W10; break; default: W=W11; break;
  }
  int c = e % dout, k = e / dout;
  wt[i*16384 + c*128 + k] = (unsigned short)f2bf(W[(size_t)k*dout + c]);
}

// ---------------- fused QKVS GEMM (bf16 MFMA, fp32 accum, 4 mats per block) ----------------
// grid: 1D row tiles. Block stages X ONCE, then loops {mat 0..3} x {col-half 0..1},
// staging the 16KB W-slice per pass (W is L2-resident). 4 waves; wave w owns a
// 16-col slice; per pass 16 MFMA 16x16x32 per wave.
__global__ __launch_bounds__(256,4) void k_gemm(
  const void* __restrict__ Xv, int xbf, int nrows,
  const unsigned short* __restrict__ Wt,
  const float* __restrict__ bq, const float* __restrict__ bk,
  const float* __restrict__ bv, const float* __restrict__ bs,
  int ws_cols, char* __restrict__ out)
{
  __shared__ unsigned short Xs[64][136];
  __shared__ unsigned short Wsh[64][136];
  int t = threadIdx.x;
  int row0 = blockIdx.x*64;
  // ---- stage X (once) ----
  {
    int r = t>>2, kb = (t&3)*32;           // 64 rows x 4 thread-chunks of 32 k
    int gr = row0 + r;
    if(gr < nrows){
      if(xbf){
        const unsigned short* xp = (const unsigned short*)Xv + (size_t)gr*DIN + kb;
        #pragma unroll
        for(int j=0;j<4;j++)
          *(uint4*)&Xs[r][kb + j*8] = *(const uint4*)(xp + j*8);
      } else {
        const float* xp = (const float*)Xv + (size_t)gr*DIN + kb;
        #pragma unroll
        for(int j=0;j<4;j++){
          float4 fa = *(const float4*)(xp + j*8);
          float4 fb = *(const float4*)(xp + j*8 + 4);
          uint4 pk = make_uint4(pack2(fa.x,fa.y), pack2(fa.z,fa.w),
                                pack2(fb.x,fb.y), pack2(fb.z,fb.w));
          *(uint4*)&Xs[r][kb + j*8] = pk;
        }
      }
    } else {
      uint4 z = make_uint4(0,0,0,0);
      #pragma unroll
      for(int j=0;j<4;j++) *(uint4*)&Xs[r][kb + j*8] = z;
    }
  }
  int wv = t>>6, l = t&63;
  int lr = l & 15, lk = (l>>4)*8;
  for(int mat=0; mat<4; mat++){
    int wcols = (mat==3)? ws_cols : 128;
    const unsigned short* Wm = Wt + mat*16384;
    const float* bias = (mat==0)?bq:(mat==1)?bk:(mat==2)?bv:bs;
    for(int half=0; half<2; half++){
      int col0 = half*64;
      if(col0 >= wcols) break;
      // ---- stage W half-slice ----
      {
        int c = t>>2, kb = (t&3)*32;
        int gc = col0 + c;
        if(gc < wcols){
          const unsigned short* wp = Wm + (size_t)gc*128 + kb;
          #pragma unroll
          for(int j=0;j<4;j++)
            *(uint4*)&Wsh[c][kb + j*8] = *(const uint4*)(wp + j*8);
        } else {
          uint4 z = make_uint4(0,0,0,0);
          #pragma unroll
          for(int j=0;j<4;j++) *(uint4*)&Wsh[c][kb + j*8] = z;
        }
      }
      __syncthreads();
      float4v acc[4];
      #pragma unroll
      for(int mt=0;mt<4;mt++) acc[mt] = (float4v){0.f,0.f,0.f,0.f};
      #pragma unroll
      for(int kk=0;kk<4;kk++){
        short8v b = *(const short8v*)&Wsh[wv*16 + lr][kk*32 + lk];
        #pragma unroll
        for(int mt=0;mt<4;mt++){
          short8v a = *(const short8v*)&Xs[mt*16 + lr][kk*32 + lk];
          acc[mt] = __builtin_amdgcn_mfma_f32_16x16x32_bf16(a, b, acc[mt], 0, 0, 0);
        }
      }
      // ---- epilogue: bias + store (Q bf16 linear; K,V bf16 chunked; S fp32) ----
      int col = col0 + wv*16 + lr;
      bool cok = col < wcols;
      float bcol = cok ? bias[col] : 0.f;
      int rb = row0 + (l>>4)*4;
      #pragma unroll
      for(int mt=0;mt<4;mt++){
        #pragma unroll
        for(int j=0;j<4;j++){
          int r = rb + mt*16 + j;
          if(r < nrows && cok){
            float val = acc[mt][j] + bcol;
            char* rowp = out + (size_t)r*ROW_BYTES;
            if(mat==0)      *(unsigned short*)(rowp + col*2) = (unsigned short)f2bf(val);
            else if(mat==3) *(float*)(rowp + 768 + col*4) = val;
            else {
              int h = col>>5, d = col&31;
              int off = ((mat==1)?256:512) + (d>>3)*64 + h*16 + (d&7)*2;
              *(unsigned short*)(rowp + off) = (unsigned short)f2bf(val);
            }
          }
        }
      }
      __syncthreads();   // before next W stage overwrites Wsh
    }
  }
}

// ---------------- per-node attention (online softmax, CSR, chunk-transposed bf16 KV) ----------------
// one wave per node; lane = e_l*4 + h. Gather: 4 head-lanes of an edge read ONE
// contiguous 64B sector per instruction. End: reduce-scatter (30 shfl) -> lane
// owns channels (2*e_l, 2*e_l+1) of head h.
// mode 0: out bf16-packed [N][64] uints = relu(concat agg + skip)
// mode 1: out fp32 [N][32] = mean_h(agg) + skip
__global__ __launch_bounds__(256,4) void k_attn(
  const char* __restrict__ QKVS, const int* __restrict__ offs,
  const int* __restrict__ srcs, void* __restrict__ outv, int mode, int n)
{
  int wv = threadIdx.x>>6, lane = threadIdx.x&63;
  int node = blockIdx.x*4 + wv;
  if(node >= n) return;
  int h = lane & 3;
  int e_l = lane >> 2;
  const float rs = 0.17677669529663687f;  // 1/sqrt(32)
  const char* rowq = QKVS + (size_t)node*ROW_BYTES + h*64;
  float4 q[8];
  #pragma unroll
  for(int j=0;j<4;j++){
    uint4 qw = *(const uint4*)(rowq + j*16);
    q[2*j]   = make_float4(bflo(qw.x)*rs, bfhi(qw.x)*rs, bflo(qw.y)*rs, bfhi(qw.y)*rs);
    q[2*j+1] = make_float4(bflo(qw.z)*rs, bfhi(qw.z)*rs, bflo(qw.w)*rs, bfhi(qw.w)*rs);
  }
  int beg = offs[node], end = offs[node+1];
  float m = -__builtin_inff(), s = 0.f;
  float4 acc[8];
  #pragma unroll
  for(int j=0;j<8;j++) acc[j] = make_float4(0.f,0.f,0.f,0.f);

  for(int b0 = beg; b0 < end; b0 += 16){
    int idx = b0 + e_l;
    bool valid = idx < end;
    int sj = srcs[valid ? idx : beg];
    const char* base = QKVS + (size_t)sj*ROW_BYTES + 256 + h*16;  // K chunks; V at +256
    // V chunks first, pinned live across dot+softmax
    uint4 vw[4];
    #pragma unroll
    for(int j=0;j<4;j++) vw[j] = *(const uint4*)(base + 256 + j*64);
    #pragma unroll
    for(int j=0;j<4;j++)
      asm volatile("" : "+v"(vw[j].x), "+v"(vw[j].y), "+v"(vw[j].z), "+v"(vw[j].w));
    float dot = 0.f;
    #pragma unroll
    for(int j=0;j<4;j++){
      uint4 kw = *(const uint4*)(base + j*64);
      float4 qa = q[2*j], qb = q[2*j+1];
      dot += qa.x*bflo(kw.x) + qa.y*bfhi(kw.x) + qa.z*bflo(kw.y) + qa.w*bfhi(kw.y);
      dot += qb.x*bflo(kw.z) + qb.y*bfhi(kw.z) + qb.z*bflo(kw.w) + qb.w*bfhi(kw.w);
    }
    float logit = valid ? dot : -__builtin_inff();
    float bm = logit;
    bm = fmaxf(bm, __shfl_xor(bm,4));
    bm = fmaxf(bm, __shfl_xor(bm,8));
    bm = fmaxf(bm, __shfl_xor(bm,16));
    bm = fmaxf(bm, __shfl_xor(bm,32));
    float mn = fmaxf(m, bm);
    float r = __expf(m - mn);       // m=-inf -> 0
    float p = __expf(logit - mn);   // invalid lanes -> 0
    float ps = p;
    ps += __shfl_xor(ps,4); ps += __shfl_xor(ps,8); ps += __shfl_xor(ps,16); ps += __shfl_xor(ps,32);
    s = r*s + ps; m = mn;
    #pragma unroll
    for(int j=0;j<4;j++){
      uint4 w = vw[j];
      float4 a0 = acc[2*j], a1 = acc[2*j+1];
      a0.x = fmaf(a0.x, r, p*bflo(w.x)); a0.y = fmaf(a0.y, r, p*bfhi(w.x));
      a0.z = fmaf(a0.z, r, p*bflo(w.y)); a0.w = fmaf(a0.w, r, p*bfhi(w.y));
      a1.x = fmaf(a1.x, r, p*bflo(w.z)); a1.y = fmaf(a1.y, r, p*bfhi(w.z));
      a1.z = fmaf(a1.z, r, p*bflo(w.w)); a1.w = fmaf(a1.w, r, p*bfhi(w.w));
      acc[2*j] = a0; acc[2*j+1] = a1;
    }
  }
  // ---- reduce-scatter over edge lanes: 30 shfl total ----
  int b5 = (lane>>5)&1, b4 = (lane>>4)&1, b3 = (lane>>3)&1, b2 = (lane>>2)&1;
  float4 r4[4];
  #pragma unroll
  for(int j=0;j<4;j++){
    float4 keep = b5 ? acc[j+4] : acc[j];
    float4 send = b5 ? acc[j]   : acc[j+4];
    keep.x += __shfl_xor(send.x,32); keep.y += __shfl_xor(send.y,32);
    keep.z += __shfl_xor(send.z,32); keep.w += __shfl_xor(send.w,32);
    r4[j] = keep;   // ch = 16*b5 + 4*j + c
  }
  float4 r2[2];
  #pragma unroll
  for(int j=0;j<2;j++){
    float4 keep = b4 ? r4[j+2] : r4[j];
    float4 send = b4 ? r4[j]   : r4[j+2];
    keep.x += __shfl_xor(send.x,16); keep.y += __shfl_xor(send.y,16);
    keep.z += __shfl_xor(send.z,16); keep.w += __shfl_xor(send.w,16);
    r2[j] = keep;   // ch = 16*b5 + 8*b4 + 4*j + c
  }
  float4 r1;
  {
    float4 keep = b3 ? r2[1] : r2[0];
    float4 send = b3 ? r2[0] : r2[1];
    keep.x += __shfl_xor(send.x,8); keep.y += __shfl_xor(send.y,8);
    keep.z += __shfl_xor(send.z,8); keep.w += __shfl_xor(send.w,8);
    r1 = keep;      // ch = 16*b5 + 8*b4 + 4*b3 + c
  }
  float fx, fy;
  {
    float kx = b2 ? r1.z : r1.x, ky = b2 ? r1.w : r1.y;
    float sx = b2 ? r1.x : r1.z, sy = b2 ? r1.y : r1.w;
    fx = kx + __shfl_xor(sx,4);
    fy = ky + __shfl_xor(sy,4);   // ch pair = (2*e_l, 2*e_l+1) of head h
  }
  float inv = (s > 0.f) ? (1.f/s) : 0.f;   // per-head (s reduced over e-lanes only)
  if(mode == 0){
    const float* sk = (const float*)(QKVS + (size_t)node*ROW_BYTES + 768);
    float2 sv = *(const float2*)(sk + h*32 + 2*e_l);
    float ox = fmaxf(fmaf(fx, inv, sv.x), 0.f);
    float oy = fmaxf(fmaf(fy, inv, sv.y), 0.f);
    ((unsigned*)outv)[(size_t)node*64 + h*16 + e_l] = pack2(ox, oy);
  } else {
    float sc = inv*0.25f;
    float ox = fx*sc, oy = fy*sc;
    ox += __shfl_xor(ox,1); oy += __shfl_xor(oy,1);
    ox += __shfl_xor(ox,2); oy += __shfl_xor(oy,2);
    if(h == 0){
      const float* sk = (const float*)(QKVS + (size_t)node*ROW_BYTES + 768);
      float2 sv = *(const float2*)(sk + 2*e_l);
      float* op = (float*)outv + (size_t)node*32 + 2*e_l;
      op[0] = ox + sv.x; op[1] = oy + sv.y;
    }
  }
}

extern "C" void kernel_launch(void* const* d_in, const int* in_sizes, int n_in,
                              void* d_out, int out_size, void* d_ws, size_t ws_size,
                              hipStream_t stream) {
  const float* x = (const float*)d_in[0];
  const int* ei = (const int*)d_in[1];
  int n = in_sizes[0]/DIN;
  int E = in_sizes[1]/2;
  const int* esrc = ei;
  const int* edst = ei + E;

  char* w = (char*)d_ws;
  auto alloc = [&](size_t bytes)->char*{
    char* p = w; w += (bytes + 255) & ~(size_t)255; return p;
  };
  int* offs = (int*)alloc((size_t)(n+1)*4);
  int* deg  = (int*)alloc((size_t)n*4);
  int* cur  = (int*)alloc((size_t)n*4);
  int* part = (int*)alloc(256*4);
  int* srcs = (int*)alloc((size_t)E*4);
  char* qkvs = alloc((size_t)n*ROW_BYTES);
  unsigned short* h1 = (unsigned short*)alloc((size_t)n*128*2);
  unsigned short* h2 = (unsigned short*)alloc((size_t)n*128*2);
  unsigned short* wt = (unsigned short*)alloc((size_t)12*16384*2);

  auto f = [&](int i)->const float*{ return (const float*)d_in[i]; };

  // weight prep (bf16, transposed)
  hipLaunchKernelGGL(k_wt, dim3(64,12), dim3(256), 0, stream,
                     f(2),f(4),f(6),f(8), f(10),f(12),f(14),f(16), f(18),f(20),f(22),f(24), wt);

  int SB = (n+255)/256;  // <=256 required for 2-level scan
  hipLaunchKernelGGL(k_zero, dim3((n+255)/256), dim3(256), 0, stream, deg, n);
  hipLaunchKernelGGL(k_zero, dim3((n+255)/256), dim3(256), 0, stream, cur, n);
  hipLaunchKernelGGL(k_count, dim3((E+255)/256), dim3(256), 0, stream, edst, deg, E);
  hipLaunchKernelGGL(k_scan1, dim3(SB), dim3(256), 0, stream, deg, offs, part, n);
  hipLaunchKernelGGL(k_scan2, dim3(1), dim3(256), 0, stream, part, SB);
  hipLaunchKernelGGL(k_scan3, dim3(SB), dim3(256), 0, stream, offs, part, n);
  hipLaunchKernelGGL(k_scatter, dim3((E+255)/256), dim3(256), 0, stream, esrc, edst, offs, cur, srcs, E);

  int RT = (n+63)/64;
  int AB = (n+3)/4;

  // layer 0
  hipLaunchKernelGGL(k_gemm, dim3(RT), dim3(256), 0, stream,
                     (const void*)x, 0, n, wt + 0*4*16384, f(3),f(5),f(7),f(9), 128, qkvs);
  hipLaunchKernelGGL(k_attn, dim3(AB), dim3(256), 0, stream, qkvs, offs, srcs, (void*)h1, 0, n);
  // layer 1
  hipLaunchKernelGGL(k_gemm, dim3(RT), dim3(256), 0, stream,
                     (const void*)h1, 1, n, wt + 1*4*16384, f(11),f(13),f(15),f(17), 128, qkvs);
  hipLaunchKernelGGL(k_attn, dim3(AB), dim3(256), 0, stream, qkvs, offs, srcs, (void*)h2, 0, n);
  // layer 2 (skip width 32, mean over heads)
  hipLaunchKernelGGL(k_gemm, dim3(RT), dim3(256), 0, stream,
                     (const void*)h2, 1, n, wt + 2*4*16384, f(19),f(21),f(23),f(25), 32, qkvs);
  hipLaunchKernelGGL(k_attn, dim3(AB), dim3(256), 0, stream, qkvs, offs, srcs, d_out, 1, n);
}